// Round 6
// baseline (200.442 us; speedup 1.0000x reference)
//
#include <hip/hip_runtime.h>

#define HWSZ   16384
#define CIN    64
#define CD     128
#define COUT   64
#define BN_EPS 1e-5f

typedef __attribute__((ext_vector_type(8))) short short8x;
typedef __attribute__((ext_vector_type(4))) float floatx4;

// ws layout (float offsets):
//      0 : wAB bf16 [256][64]  (pre o0..127 | atten o128..255, [o][c] row-major)
//  16384 : wP  bf16 [64][128]
//  24576 : disp[128][6]
//  25344 : a_stats[256]
//  25600 : o_stats[128]
//  25728 : spat[2048]
//  32768 : big region (64 MiB): out_pre -> m -> skipS (channel slots 0..63)
#define WS_WT1   0
#define WS_WTP   16384
#define WS_DISP  24576
#define WS_ASTAT 25344
#define WS_OSTAT 25600
#define WS_SPAT  25728
#define WS_BIG   32768
#define WS_TOTAL_BYTES ((size_t)(32768 + 16777216) * 4)

__device__ __forceinline__ unsigned short f2bf(float f) {
    unsigned int u = __float_as_uint(f);
    u += 0x7fff + ((u >> 16) & 1);
    return (unsigned short)(u >> 16);
}
__device__ __forceinline__ float bf2f(unsigned short s) {
    return __uint_as_float(((unsigned int)s) << 16);
}
__device__ __forceinline__ float softplus_fast(float x) {
    return fmaxf(x, 0.f) + __logf(1.f + __expf(-fabsf(x)));
}
__device__ __forceinline__ float block_reduce(float v, float* sc) {
    #pragma unroll
    for (int off = 32; off >= 1; off >>= 1) v += __shfl_xor(v, off, 64);
    int wv = threadIdx.x >> 6, ln = threadIdx.x & 63;
    if (ln == 0) sc[wv] = v;
    __syncthreads();
    float r = (threadIdx.x < 4) ? sc[threadIdx.x] : 0.f;
    r += __shfl_xor(r, 1, 64);
    r += __shfl_xor(r, 2, 64);
    return r;
}

// ---------------- K0: weights->bf16 + displacement params ----------------
__global__ __launch_bounds__(256) void prep_kernel(
        const float* __restrict__ pre_w, const float* __restrict__ atten_w,
        const float* __restrict__ post_w, const float* __restrict__ offsets,
        float* __restrict__ ws) {
    int tid = blockIdx.x * 256 + threadIdx.x;
    unsigned short* wAB = (unsigned short*)(ws + WS_WT1);
    unsigned short* wP  = (unsigned short*)(ws + WS_WTP);
    float* disp = ws + WS_DISP;
    if (tid < 16384) {
        int o = tid >> 6, c = tid & 63;
        float v = (o < 128) ? pre_w[o * 64 + c] : atten_w[(o - 128) * 64 + c];
        wAB[tid] = f2bf(v);
    } else if (tid < 24576) {
        int k = tid - 16384;
        int o = k >> 7, c = k & 127;
        wP[k] = f2bf(post_w[o * 128 + c]);
    } else if (tid < 24704) {
        int c = tid - 24576;
        float dy = offsets[(c >> 2) * 2 + 0];
        float dx = offsets[(c >> 2) * 2 + 1];
        float fy = floorf(dy), fx = floorf(dx);
        float wy = dy - fy, wx = dx - fx;
        float* d = disp + c * 6;
        d[0] = fy; d[1] = fx;
        d[2] = (1.f - wy) * (1.f - wx);
        d[3] = (1.f - wy) * wx;
        d[4] = wy * (1.f - wx);
        d[5] = wy * wx;
    }
}

// ---------------- K1: MFMA conv1x1 (pre + atten), D = [px][o] ----------------
// mfma(A=x, B=w): lane holds D rows (px) = (ln>>4)*4+reg, col (o) = ln&15
// -> ushort4 (4 consecutive px, one o) packed global stores.
__global__ __launch_bounds__(256) void conv_pre_mfma(
        const float* __restrict__ x, const unsigned short* __restrict__ wAB,
        const float* __restrict__ pre_b, const float* __restrict__ atten_b,
        unsigned short* __restrict__ out_pre, unsigned short* __restrict__ a_out) {
    __shared__ unsigned short xT[64 * 72];   // [px][c], row 72 bf16 = 144B
    int t = threadIdx.x;
    int wv = t >> 6, ln = t & 63;
    int P0 = blockIdx.x * 64;
    int b = P0 >> 14, poff = P0 & 16383;
    const float* xg = x + (size_t)b * CIN * HWSZ + poff;
    int c = ln;
    #pragma unroll
    for (int k = 0; k < 4; ++k) {
        int px = wv * 16 + k * 4;
        float4 v = *(const float4*)(xg + (size_t)c * HWSZ + px);
        xT[(px + 0) * 72 + c] = f2bf(v.x);
        xT[(px + 1) * 72 + c] = f2bf(v.y);
        xT[(px + 2) * 72 + c] = f2bf(v.z);
        xT[(px + 3) * 72 + c] = f2bf(v.w);
    }
    __syncthreads();
    int o0 = wv * 64;
    short8x wfrag[4][2];   // B-operand: lane col o = ln&15, k contiguous
    #pragma unroll
    for (int oi = 0; oi < 4; ++oi)
        #pragma unroll
        for (int kk = 0; kk < 2; ++kk) {
            int row = o0 + oi * 16 + (ln & 15);
            int kcol = kk * 32 + (ln >> 4) * 8;
            wfrag[oi][kk] = *(const short8x*)(wAB + row * 64 + kcol);
        }
    floatx4 acc[4][4];
    #pragma unroll
    for (int oi = 0; oi < 4; ++oi) {
        int og = o0 + oi * 16;
        float bv = (og < 128) ? pre_b[og + (ln & 15)] : atten_b[og - 128 + (ln & 15)];
        #pragma unroll
        for (int pi = 0; pi < 4; ++pi)
            acc[oi][pi] = floatx4{bv, bv, bv, bv};
    }
    #pragma unroll
    for (int kk = 0; kk < 2; ++kk)
        #pragma unroll
        for (int pi = 0; pi < 4; ++pi) {
            short8x xfrag = *(const short8x*)((const char*)xT +
                    (pi * 16 + (ln & 15)) * 144 + (kk * 32 + (ln >> 4) * 8) * 2);
            #pragma unroll
            for (int oi = 0; oi < 4; ++oi)
                acc[oi][pi] = __builtin_amdgcn_mfma_f32_16x16x32_bf16(
                        xfrag, wfrag[oi][kk], acc[oi][pi], 0, 0, 0);
        }
    #pragma unroll
    for (int oi = 0; oi < 4; ++oi) {
        int og = o0 + oi * 16;
        unsigned short* dst = (og < 128) ? out_pre : a_out;
        int o = ((og < 128) ? og : og - 128) + (ln & 15);
        #pragma unroll
        for (int pi = 0; pi < 4; ++pi) {
            int pxl = pi * 16 + (ln >> 4) * 4;
            ushort4 o4;
            o4.x = f2bf(acc[oi][pi][0]); o4.y = f2bf(acc[oi][pi][1]);
            o4.z = f2bf(acc[oi][pi][2]); o4.w = f2bf(acc[oi][pi][3]);
            *(ushort4*)(dst + ((size_t)b * CD + o) * HWSZ + poff + pxl) = o4;
        }
    }
}

// ---------------- per-channel sum/sumsq over bf16 src ----------------
__global__ __launch_bounds__(256) void chan_stats_bf16(
        const unsigned short* __restrict__ src, float* __restrict__ stats) {
    __shared__ float sc1[8], sc2[8];
    int c = blockIdx.x, b = blockIdx.y;
    const unsigned short* base = src + ((size_t)b * CD + c) * HWSZ;
    int t = threadIdx.x;
    float sum = 0.f, sq = 0.f;
    #pragma unroll
    for (int i = 0; i < 8; ++i) {
        uint4 v = *(const uint4*)(base + i * 2048 + t * 8);
        unsigned int u[4] = {v.x, v.y, v.z, v.w};
        #pragma unroll
        for (int k = 0; k < 4; ++k) {
            float lo = bf2f((unsigned short)(u[k] & 0xffff));
            float hi = bf2f((unsigned short)(u[k] >> 16));
            sum += lo + hi;
            sq  += lo * lo + hi * hi;
        }
    }
    sum = block_reduce(sum, sc1);
    __syncthreads();
    sq = block_reduce(sq, sc2);
    if (t == 0) {
        atomicAdd(&stats[c * 2 + 0], sum);
        atomicAdd(&stats[c * 2 + 1], sq);
    }
}

// ---------------- BN -> softplus in place (bf16) + spatial sums ----------------
__global__ __launch_bounds__(256) void bn_softplus(
        unsigned int* __restrict__ a, const float* __restrict__ stats,
        const float* __restrict__ g, const float* __restrict__ bb,
        float* __restrict__ spat) {
    __shared__ float sc[8];
    int bc = blockIdx.x;
    int c = bc & 127;
    const float N = 262144.f;
    float mean = stats[c * 2] / N;
    float var  = stats[c * 2 + 1] / N - mean * mean;
    float rstd = rsqrtf(var + BN_EPS);
    float scl = rstd * g[c];
    float shf = bb[c] - mean * scl;
    unsigned int* base = a + (size_t)bc * (HWSZ / 2);
    int t = threadIdx.x;
    float lsum = 0.f;
    #pragma unroll 2
    for (int i = 0; i < 8; ++i) {
        uint4 v = *(uint4*)(base + i * 1024 + t * 4);
        unsigned int* u = (unsigned int*)&v;
        #pragma unroll
        for (int k = 0; k < 4; ++k) {
            float lo = bf2f((unsigned short)(u[k] & 0xffff));
            float hi = bf2f((unsigned short)(u[k] >> 16));
            lo = softplus_fast(lo * scl + shf);
            hi = softplus_fast(hi * scl + shf);
            lsum += lo + hi;
            u[k] = (unsigned int)f2bf(lo) | ((unsigned int)f2bf(hi) << 16);
        }
        *(uint4*)(base + i * 1024 + t * 4) = v;
    }
    lsum = block_reduce(lsum, sc);
    if (t == 0) spat[bc] = lsum;
}

// ---------------- displace * normalized atten, IN PLACE over out_pre ----------------
struct Win9 { float v0,v1,v2,v3,v4,v5,v6,v7,v8; };
__device__ __forceinline__ Win9 extract9(uint4 qa, uint4 qb, bool s4, int sh) {
    unsigned long long A0 = ((unsigned long long)qa.y << 32) | qa.x;
    unsigned long long A1 = ((unsigned long long)qa.w << 32) | qa.z;
    unsigned long long A2 = ((unsigned long long)qb.y << 32) | qb.x;
    unsigned long long A3 = ((unsigned long long)qb.w << 32) | qb.z;
    unsigned long long B0 = s4 ? A1 : A0;
    unsigned long long B1 = s4 ? A2 : A1;
    unsigned long long B2 = s4 ? A3 : A2;
    unsigned long long r0 = sh ? ((B0 >> sh) | (B1 << (64 - sh))) : B0;
    unsigned long long r1 = sh ? ((B1 >> sh) | (B2 << (64 - sh))) : B1;
    unsigned int v8w = (unsigned int)(sh ? (B2 >> sh) : B2);
    Win9 w;
    w.v0 = bf2f((unsigned short)(r0 >>  0)); w.v1 = bf2f((unsigned short)(r0 >> 16));
    w.v2 = bf2f((unsigned short)(r0 >> 32)); w.v3 = bf2f((unsigned short)(r0 >> 48));
    w.v4 = bf2f((unsigned short)(r1 >>  0)); w.v5 = bf2f((unsigned short)(r1 >> 16));
    w.v6 = bf2f((unsigned short)(r1 >> 32)); w.v7 = bf2f((unsigned short)(r1 >> 48));
    w.v8 = bf2f((unsigned short)(v8w & 0xffff));
    return w;
}

__global__ __launch_bounds__(256) void displace_mul(
        unsigned short* __restrict__ pre, const unsigned short* __restrict__ a_sp,
        const float* __restrict__ spat, const float* __restrict__ disp) {
    __shared__ unsigned short img[128 * 136];
    int bc = blockIdx.x;
    int cc = bc & 127;
    const float* d = disp + cc * 6;
    int iy = (int)d[0], ix = (int)d[1];
    float w00 = d[2], w01 = d[3], w10 = d[4], w11 = d[5];
    float inv = 1.f / spat[bc];
    unsigned short* pb = pre + (size_t)bc * HWSZ;
    const unsigned short* ab = a_sp + (size_t)bc * HWSZ;
    int t = threadIdx.x;
    #pragma unroll
    for (int i = 0; i < 8; ++i) {
        int px = i * 2048 + t * 8;
        uint4 v = *(const uint4*)(pb + px);
        int y = px >> 7, xx = px & 127;
        *(uint4*)&img[y * 136 + xx] = v;
    }
    __syncthreads();
    int s = ix & 7;
    int ix8 = ix - s;
    int sh = (s & 3) * 16;
    bool s4 = s >= 4;
    for (int i = 0; i < 8; ++i) {
        int px = i * 2048 + t * 8;
        int y = px >> 7, x0 = px & 127;
        int yy0 = y + iy, yy1 = yy0 + 1;
        float wA0 = (yy0 >= 0 && yy0 < 128) ? w00 : 0.f;
        float wA1 = (yy0 >= 0 && yy0 < 128) ? w01 : 0.f;
        float wB0 = (yy1 >= 0 && yy1 < 128) ? w10 : 0.f;
        float wB1 = (yy1 >= 0 && yy1 < 128) ? w11 : 0.f;
        int yc0 = min(max(yy0, 0), 127), yc1 = min(max(yy1, 0), 127);
        int w0 = x0 + ix8;
        uint4 z = {0u, 0u, 0u, 0u};
        uint4 qa0 = (w0 >= 0 && w0 <= 120)         ? *(const uint4*)&img[yc0 * 136 + w0]     : z;
        uint4 qa1 = (w0 + 8 >= 0 && w0 + 8 <= 120) ? *(const uint4*)&img[yc0 * 136 + w0 + 8] : z;
        uint4 qb0 = (w0 >= 0 && w0 <= 120)         ? *(const uint4*)&img[yc1 * 136 + w0]     : z;
        uint4 qb1 = (w0 + 8 >= 0 && w0 + 8 <= 120) ? *(const uint4*)&img[yc1 * 136 + w0 + 8] : z;
        Win9 va = extract9(qa0, qa1, s4, sh);
        Win9 vb = extract9(qb0, qb1, s4, sh);
        float dv0 = wA0*va.v0 + wA1*va.v1 + wB0*vb.v0 + wB1*vb.v1;
        float dv1 = wA0*va.v1 + wA1*va.v2 + wB0*vb.v1 + wB1*vb.v2;
        float dv2 = wA0*va.v2 + wA1*va.v3 + wB0*vb.v2 + wB1*vb.v3;
        float dv3 = wA0*va.v3 + wA1*va.v4 + wB0*vb.v3 + wB1*vb.v4;
        float dv4 = wA0*va.v4 + wA1*va.v5 + wB0*vb.v4 + wB1*vb.v5;
        float dv5 = wA0*va.v5 + wA1*va.v6 + wB0*vb.v5 + wB1*vb.v6;
        float dv6 = wA0*va.v6 + wA1*va.v7 + wB0*vb.v6 + wB1*vb.v7;
        float dv7 = wA0*va.v7 + wA1*va.v8 + wB0*vb.v7 + wB1*vb.v8;
        uint4 av = *(const uint4*)(ab + px);
        unsigned int au[4] = {av.x, av.y, av.z, av.w};
        float a0 = bf2f((unsigned short)(au[0] & 0xffff)) * inv;
        float a1 = bf2f((unsigned short)(au[0] >> 16)) * inv;
        float a2 = bf2f((unsigned short)(au[1] & 0xffff)) * inv;
        float a3 = bf2f((unsigned short)(au[1] >> 16)) * inv;
        float a4 = bf2f((unsigned short)(au[2] & 0xffff)) * inv;
        float a5 = bf2f((unsigned short)(au[2] >> 16)) * inv;
        float a6 = bf2f((unsigned short)(au[3] & 0xffff)) * inv;
        float a7 = bf2f((unsigned short)(au[3] >> 16)) * inv;
        uint4 o;
        o.x = (unsigned int)f2bf(dv0 * a0) | ((unsigned int)f2bf(dv1 * a1) << 16);
        o.y = (unsigned int)f2bf(dv2 * a2) | ((unsigned int)f2bf(dv3 * a3) << 16);
        o.z = (unsigned int)f2bf(dv4 * a4) | ((unsigned int)f2bf(dv5 * a5) << 16);
        o.w = (unsigned int)f2bf(dv6 * a6) | ((unsigned int)f2bf(dv7 * a7) << 16);
        *(uint4*)(pb + px) = o;
    }
}

// ---------------- MFMA conv 128->64 + bias + skip -> skipS, D = [px][o] ----------------
__global__ __launch_bounds__(256) void conv_post_mfma(
        const unsigned short* __restrict__ m, const unsigned short* __restrict__ wP,
        const float* __restrict__ post_b, const float* __restrict__ x,
        unsigned short* __restrict__ skipS) {
    __shared__ unsigned short mT[128 * 128];  // byte = px*256 + ((c*2) ^ ((px&7)<<4))
    int t = threadIdx.x;
    int P0 = blockIdx.x * 128;
    int b = P0 >> 14, poff = P0 & 16383;
    int cl = t & 31, q = t >> 5;
    #pragma unroll
    for (int pass = 0; pass < 4; ++pass) {
        int c = cl + pass * 32;
        const unsigned short* mrow = m + ((size_t)b * CD + c) * HWSZ + poff;
        #pragma unroll
        for (int h = 0; h < 2; ++h) {
            int px0 = h * 64 + q * 8;
            uint4 v = *(const uint4*)(mrow + px0);
            unsigned int u[4] = {v.x, v.y, v.z, v.w};
            #pragma unroll
            for (int j = 0; j < 8; ++j) {
                unsigned short val = (unsigned short)((u[j >> 1] >> ((j & 1) * 16)) & 0xffff);
                int byteoff = (px0 + j) * 256 + ((c * 2) ^ (j << 4));
                *(unsigned short*)((char*)mT + byteoff) = val;
            }
        }
    }
    __syncthreads();
    int ln = t & 63, wv = t >> 6;
    int o0 = (wv >> 1) * 32;
    int ph = (wv & 1) * 64;
    short8x aw[2][4];   // B-operand (weights): lane col o = ln&15
    #pragma unroll
    for (int oi = 0; oi < 2; ++oi)
        #pragma unroll
        for (int kk = 0; kk < 4; ++kk)
            aw[oi][kk] = *(const short8x*)(wP + (o0 + oi * 16 + (ln & 15)) * 128 + kk * 32 + (ln >> 4) * 8);
    floatx4 acc[2][4];
    #pragma unroll
    for (int oi = 0; oi < 2; ++oi)
        #pragma unroll
        for (int pi = 0; pi < 4; ++pi) acc[oi][pi] = floatx4{0.f, 0.f, 0.f, 0.f};
    #pragma unroll
    for (int kk = 0; kk < 4; ++kk)
        #pragma unroll
        for (int pi = 0; pi < 4; ++pi) {
            int px = ph + pi * 16 + (ln & 15);
            int cb = kk * 64 + (ln >> 4) * 16;
            short8x mf = *(const short8x*)((const char*)mT + px * 256 + (cb ^ ((px & 7) << 4)));
            #pragma unroll
            for (int oi = 0; oi < 2; ++oi)
                acc[oi][pi] = __builtin_amdgcn_mfma_f32_16x16x32_bf16(mf, aw[oi][kk], acc[oi][pi], 0, 0, 0);
        }
    #pragma unroll
    for (int oi = 0; oi < 2; ++oi) {
        int o = o0 + oi * 16 + (ln & 15);
        float bv = post_b[o];
        #pragma unroll
        for (int pi = 0; pi < 4; ++pi) {
            int pxg = poff + ph + pi * 16 + (ln >> 4) * 4;
            float4 xv = *(const float4*)(x + ((size_t)b * COUT + o) * HWSZ + pxg);
            ushort4 s4v;
            s4v.x = f2bf(acc[oi][pi][0] + bv + xv.x);
            s4v.y = f2bf(acc[oi][pi][1] + bv + xv.y);
            s4v.z = f2bf(acc[oi][pi][2] + bv + xv.z);
            s4v.w = f2bf(acc[oi][pi][3] + bv + xv.w);
            *(ushort4*)(skipS + ((size_t)b * CD + o) * HWSZ + pxg) = s4v;
        }
    }
}

// ---------------- final BN + ReLU: skipS bf16 -> d_out fp32 ----------------
__global__ __launch_bounds__(256) void bn_relu_out(
        const unsigned short* __restrict__ skipS, float* __restrict__ out,
        const float* __restrict__ stats, const float* __restrict__ g,
        const float* __restrict__ bb) {
    const float N = 262144.f;
    int t = threadIdx.x;
    #pragma unroll
    for (int k = 0; k < 4; ++k) {
        size_t gidx = (size_t)blockIdx.x * 1024 + k * 256 + t;  // 8-elem index
        size_t e = gidx * 8;
        int b = (int)(e >> 20);
        int c = (int)(e >> 14) & 63;
        int px = (int)(e & 16383);
        float mean = stats[c * 2] / N;
        float rstd = rsqrtf(stats[c * 2 + 1] / N - mean * mean + BN_EPS);
        float gc = g[c], bbc = bb[c];
        uint4 v = *(const uint4*)(skipS + ((size_t)b * CD + c) * HWSZ + px);
        unsigned int u[4] = {v.x, v.y, v.z, v.w};
        float4 o0, o1;
        float* op[8] = {&o0.x, &o0.y, &o0.z, &o0.w, &o1.x, &o1.y, &o1.z, &o1.w};
        #pragma unroll
        for (int j = 0; j < 8; ++j) {
            float val = bf2f((unsigned short)((u[j >> 1] >> ((j & 1) * 16)) & 0xffff));
            *op[j] = fmaxf((val - mean) * rstd * gc + bbc, 0.f);
        }
        *(float4*)(out + e) = o0;
        *(float4*)(out + e + 4) = o1;
    }
}

extern "C" void kernel_launch(void* const* d_in, const int* in_sizes, int n_in,
                              void* d_out, int out_size, void* d_ws, size_t ws_size,
                              hipStream_t stream) {
    const float* x          = (const float*)d_in[0];
    const float* pre_w      = (const float*)d_in[1];
    const float* pre_b      = (const float*)d_in[2];
    const float* post_w     = (const float*)d_in[3];
    const float* post_b     = (const float*)d_in[4];
    const float* atten_w    = (const float*)d_in[5];
    const float* atten_b    = (const float*)d_in[6];
    const float* atten_bn_g = (const float*)d_in[7];
    const float* atten_bn_b = (const float*)d_in[8];
    const float* offsets    = (const float*)d_in[9];
    const float* bn_g       = (const float*)d_in[10];
    const float* bn_b       = (const float*)d_in[11];
    float* out = (float*)d_out;
    float* ws  = (float*)d_ws;

    if (ws_size < WS_TOTAL_BYTES) return;

    unsigned short* wAB = (unsigned short*)(ws + WS_WT1);
    unsigned short* wP  = (unsigned short*)(ws + WS_WTP);
    float* disp    = ws + WS_DISP;
    float* a_stats = ws + WS_ASTAT;
    float* o_stats = ws + WS_OSTAT;
    float* spat    = ws + WS_SPAT;
    unsigned short* big   = (unsigned short*)(ws + WS_BIG);  // out_pre -> m -> skipS
    unsigned short* a_buf = (unsigned short*)d_out;          // a_raw -> a_sp (bf16)

    hipMemsetAsync((void*)a_stats, 0, 384 * sizeof(float), stream);

    prep_kernel<<<97, 256, 0, stream>>>(pre_w, atten_w, post_w, offsets, ws);
    conv_pre_mfma<<<4096, 256, 0, stream>>>(x, wAB, pre_b, atten_b, big, a_buf);
    chan_stats_bf16<<<dim3(128, 16), 256, 0, stream>>>(a_buf, a_stats);
    bn_softplus<<<2048, 256, 0, stream>>>((unsigned int*)a_buf, a_stats, atten_bn_g, atten_bn_b, spat);
    displace_mul<<<2048, 256, 0, stream>>>(big, a_buf, spat, disp);
    conv_post_mfma<<<2048, 256, 0, stream>>>(big, wP, post_b, x, big);
    chan_stats_bf16<<<dim3(64, 16), 256, 0, stream>>>(big, o_stats);
    bn_relu_out<<<2048, 256, 0, stream>>>(big, out, o_stats, bn_g, bn_b);
}

// Round 7
// 180.113 us; speedup vs baseline: 1.1129x; 1.1129x over previous
//
#include <hip/hip_runtime.h>

#define HWSZ   16384
#define CIN    64
#define CD     128
#define COUT   64
#define BN_EPS 1e-5f

typedef __attribute__((ext_vector_type(8))) short short8x;
typedef __attribute__((ext_vector_type(4))) float floatx4;

// ws layout (float offsets):
//      0 : wAB bf16 [256][64]  (pre o0..127 | atten o128..255, [o][c] row-major)
//  16384 : wP  bf16 [64][128]
//  24576 : disp[128][6]
//  25344 : a_stats[256]
//  25600 : o_stats[128]
//  25728 : spat[2048]
//  32768 : big region (64 MiB): out_pre -> m -> skipS (channel slots 0..63)
#define WS_WT1   0
#define WS_WTP   16384
#define WS_DISP  24576
#define WS_ASTAT 25344
#define WS_OSTAT 25600
#define WS_SPAT  25728
#define WS_BIG   32768
#define WS_TOTAL_BYTES ((size_t)(32768 + 16777216) * 4)

__device__ __forceinline__ unsigned short f2bf(float f) {
    unsigned int u = __float_as_uint(f);
    u += 0x7fff + ((u >> 16) & 1);
    return (unsigned short)(u >> 16);
}
__device__ __forceinline__ float bf2f(unsigned short s) {
    return __uint_as_float(((unsigned int)s) << 16);
}
__device__ __forceinline__ float softplus_fast(float x) {
    return fmaxf(x, 0.f) + __logf(1.f + __expf(-fabsf(x)));
}
__device__ __forceinline__ float block_reduce(float v, float* sc) {
    #pragma unroll
    for (int off = 32; off >= 1; off >>= 1) v += __shfl_xor(v, off, 64);
    int wv = threadIdx.x >> 6, ln = threadIdx.x & 63;
    if (ln == 0) sc[wv] = v;
    __syncthreads();
    float r = (threadIdx.x < 4) ? sc[threadIdx.x] : 0.f;
    r += __shfl_xor(r, 1, 64);
    r += __shfl_xor(r, 2, 64);
    return r;
}

// ---------------- K0: weights->bf16 + displacement params ----------------
__global__ __launch_bounds__(256) void prep_kernel(
        const float* __restrict__ pre_w, const float* __restrict__ atten_w,
        const float* __restrict__ post_w, const float* __restrict__ offsets,
        float* __restrict__ ws) {
    int tid = blockIdx.x * 256 + threadIdx.x;
    unsigned short* wAB = (unsigned short*)(ws + WS_WT1);
    unsigned short* wP  = (unsigned short*)(ws + WS_WTP);
    float* disp = ws + WS_DISP;
    if (tid < 16384) {
        int o = tid >> 6, c = tid & 63;
        float v = (o < 128) ? pre_w[o * 64 + c] : atten_w[(o - 128) * 64 + c];
        wAB[tid] = f2bf(v);
    } else if (tid < 24576) {
        int k = tid - 16384;
        int o = k >> 7, c = k & 127;
        wP[k] = f2bf(post_w[o * 128 + c]);
    } else if (tid < 24704) {
        int c = tid - 24576;
        float dy = offsets[(c >> 2) * 2 + 0];
        float dx = offsets[(c >> 2) * 2 + 1];
        float fy = floorf(dy), fx = floorf(dx);
        float wy = dy - fy, wx = dx - fx;
        float* d = disp + c * 6;
        d[0] = fy; d[1] = fx;
        d[2] = (1.f - wy) * (1.f - wx);
        d[3] = (1.f - wy) * wx;
        d[4] = wy * (1.f - wx);
        d[5] = wy * wx;
    }
}

// ---------------- K1: MFMA conv1x1 (pre + atten), 4-tile pipelined ----------------
// block = 256 px (4 tiles x 64 px); weights persist in regs; double-buffered LDS;
// stage-load(t+1) issued before compute(t), stage-write after (T14 split).
__global__ __launch_bounds__(256) void conv_pre_mfma(
        const float* __restrict__ x, const unsigned short* __restrict__ wAB,
        const float* __restrict__ pre_b, const float* __restrict__ atten_b,
        unsigned short* __restrict__ out_pre, unsigned short* __restrict__ a_out) {
    __shared__ unsigned short xT[2][64 * 72];   // [px][c], row 72 bf16 = 144B
    int t = threadIdx.x;
    int wv = t >> 6, ln = t & 63;
    int b = blockIdx.x >> 6;
    int poff = (blockIdx.x & 63) << 8;          // 256-px super-tile
    const float* xg = x + (size_t)b * CIN * HWSZ + poff;
    int c = ln;

    // persistent weight fragments + bias (B-operand style: row o, k contiguous)
    int o0 = wv * 64;
    short8x wfrag[4][2];
    #pragma unroll
    for (int oi = 0; oi < 4; ++oi)
        #pragma unroll
        for (int kk = 0; kk < 2; ++kk) {
            int row = o0 + oi * 16 + (ln & 15);
            int kcol = kk * 32 + (ln >> 4) * 8;
            wfrag[oi][kk] = *(const short8x*)(wAB + row * 64 + kcol);
        }
    float4 biasv[4];
    #pragma unroll
    for (int oi = 0; oi < 4; ++oi) {
        int og = o0 + oi * 16;
        const float* bias = (og < 128) ? (pre_b + og) : (atten_b + og - 128);
        biasv[oi] = *(const float4*)(bias + (ln >> 4) * 4);
    }

    float4 ld[4];
    // prologue: stage tile 0 -> buf 0
    #pragma unroll
    for (int k = 0; k < 4; ++k)
        ld[k] = *(const float4*)(xg + (size_t)c * HWSZ + 0 * 64 + wv * 16 + k * 4);
    #pragma unroll
    for (int k = 0; k < 4; ++k) {
        int px = wv * 16 + k * 4;
        xT[0][(px + 0) * 72 + c] = f2bf(ld[k].x);
        xT[0][(px + 1) * 72 + c] = f2bf(ld[k].y);
        xT[0][(px + 2) * 72 + c] = f2bf(ld[k].z);
        xT[0][(px + 3) * 72 + c] = f2bf(ld[k].w);
    }
    __syncthreads();

    #pragma unroll
    for (int tt = 0; tt < 4; ++tt) {
        // issue next tile's global loads early (latency hides under compute)
        if (tt < 3) {
            #pragma unroll
            for (int k = 0; k < 4; ++k)
                ld[k] = *(const float4*)(xg + (size_t)c * HWSZ + (tt + 1) * 64 + wv * 16 + k * 4);
        }
        // compute tile tt from buf tt&1
        const unsigned short* buf = xT[tt & 1];
        floatx4 acc[4][4];
        #pragma unroll
        for (int oi = 0; oi < 4; ++oi)
            #pragma unroll
            for (int pi = 0; pi < 4; ++pi)
                acc[oi][pi] = floatx4{biasv[oi].x, biasv[oi].y, biasv[oi].z, biasv[oi].w};
        #pragma unroll
        for (int kk = 0; kk < 2; ++kk)
            #pragma unroll
            for (int pi = 0; pi < 4; ++pi) {
                short8x xfrag = *(const short8x*)((const char*)buf +
                        (pi * 16 + (ln & 15)) * 144 + (kk * 32 + (ln >> 4) * 8) * 2);
                #pragma unroll
                for (int oi = 0; oi < 4; ++oi)
                    acc[oi][pi] = __builtin_amdgcn_mfma_f32_16x16x32_bf16(
                            wfrag[oi][kk], xfrag, acc[oi][pi], 0, 0, 0);
            }
        int ptile = poff + tt * 64;
        #pragma unroll
        for (int oi = 0; oi < 4; ++oi) {
            int og = o0 + oi * 16;
            unsigned short* dst = (og < 128) ? out_pre : a_out;
            int ob = (og < 128) ? og : og - 128;
            #pragma unroll
            for (int pi = 0; pi < 4; ++pi) {
                int px = ptile + pi * 16 + (ln & 15);
                #pragma unroll
                for (int r = 0; r < 4; ++r) {
                    int o = ob + (ln >> 4) * 4 + r;
                    dst[((size_t)b * CD + o) * HWSZ + px] = f2bf(acc[oi][pi][r]);
                }
            }
        }
        // write next tile into the OTHER buffer (readers of it finished last iter)
        if (tt < 3) {
            unsigned short* wbuf = xT[(tt + 1) & 1];
            #pragma unroll
            for (int k = 0; k < 4; ++k) {
                int px = wv * 16 + k * 4;
                wbuf[(px + 0) * 72 + c] = f2bf(ld[k].x);
                wbuf[(px + 1) * 72 + c] = f2bf(ld[k].y);
                wbuf[(px + 2) * 72 + c] = f2bf(ld[k].z);
                wbuf[(px + 3) * 72 + c] = f2bf(ld[k].w);
            }
        }
        __syncthreads();
    }
}

// ---------------- per-channel sum/sumsq over bf16 src ----------------
__global__ __launch_bounds__(256) void chan_stats_bf16(
        const unsigned short* __restrict__ src, float* __restrict__ stats) {
    __shared__ float sc1[8], sc2[8];
    int c = blockIdx.x, b = blockIdx.y;
    const unsigned short* base = src + ((size_t)b * CD + c) * HWSZ;
    int t = threadIdx.x;
    float sum = 0.f, sq = 0.f;
    #pragma unroll
    for (int i = 0; i < 8; ++i) {
        uint4 v = *(const uint4*)(base + i * 2048 + t * 8);
        unsigned int u[4] = {v.x, v.y, v.z, v.w};
        #pragma unroll
        for (int k = 0; k < 4; ++k) {
            float lo = bf2f((unsigned short)(u[k] & 0xffff));
            float hi = bf2f((unsigned short)(u[k] >> 16));
            sum += lo + hi;
            sq  += lo * lo + hi * hi;
        }
    }
    sum = block_reduce(sum, sc1);
    __syncthreads();
    sq = block_reduce(sq, sc2);
    if (t == 0) {
        atomicAdd(&stats[c * 2 + 0], sum);
        atomicAdd(&stats[c * 2 + 1], sq);
    }
}

// ---------------- BN -> softplus in place (bf16) + spatial sums ----------------
__global__ __launch_bounds__(256) void bn_softplus(
        unsigned int* __restrict__ a, const float* __restrict__ stats,
        const float* __restrict__ g, const float* __restrict__ bb,
        float* __restrict__ spat) {
    __shared__ float sc[8];
    int bc = blockIdx.x;
    int c = bc & 127;
    const float N = 262144.f;
    float mean = stats[c * 2] / N;
    float var  = stats[c * 2 + 1] / N - mean * mean;
    float rstd = rsqrtf(var + BN_EPS);
    float scl = rstd * g[c];
    float shf = bb[c] - mean * scl;
    unsigned int* base = a + (size_t)bc * (HWSZ / 2);
    int t = threadIdx.x;
    float lsum = 0.f;
    #pragma unroll 2
    for (int i = 0; i < 8; ++i) {
        uint4 v = *(uint4*)(base + i * 1024 + t * 4);
        unsigned int* u = (unsigned int*)&v;
        #pragma unroll
        for (int k = 0; k < 4; ++k) {
            float lo = bf2f((unsigned short)(u[k] & 0xffff));
            float hi = bf2f((unsigned short)(u[k] >> 16));
            lo = softplus_fast(lo * scl + shf);
            hi = softplus_fast(hi * scl + shf);
            lsum += lo + hi;
            u[k] = (unsigned int)f2bf(lo) | ((unsigned int)f2bf(hi) << 16);
        }
        *(uint4*)(base + i * 1024 + t * 4) = v;
    }
    lsum = block_reduce(lsum, sc);
    if (t == 0) spat[bc] = lsum;
}

// ---------------- displace * normalized atten, IN PLACE over out_pre ----------------
struct Win9 { float v0,v1,v2,v3,v4,v5,v6,v7,v8; };
__device__ __forceinline__ Win9 extract9(uint4 qa, uint4 qb, bool s4, int sh) {
    unsigned long long A0 = ((unsigned long long)qa.y << 32) | qa.x;
    unsigned long long A1 = ((unsigned long long)qa.w << 32) | qa.z;
    unsigned long long A2 = ((unsigned long long)qb.y << 32) | qb.x;
    unsigned long long A3 = ((unsigned long long)qb.w << 32) | qb.z;
    unsigned long long B0 = s4 ? A1 : A0;
    unsigned long long B1 = s4 ? A2 : A1;
    unsigned long long B2 = s4 ? A3 : A2;
    unsigned long long r0 = sh ? ((B0 >> sh) | (B1 << (64 - sh))) : B0;
    unsigned long long r1 = sh ? ((B1 >> sh) | (B2 << (64 - sh))) : B1;
    unsigned int v8w = (unsigned int)(sh ? (B2 >> sh) : B2);
    Win9 w;
    w.v0 = bf2f((unsigned short)(r0 >>  0)); w.v1 = bf2f((unsigned short)(r0 >> 16));
    w.v2 = bf2f((unsigned short)(r0 >> 32)); w.v3 = bf2f((unsigned short)(r0 >> 48));
    w.v4 = bf2f((unsigned short)(r1 >>  0)); w.v5 = bf2f((unsigned short)(r1 >> 16));
    w.v6 = bf2f((unsigned short)(r1 >> 32)); w.v7 = bf2f((unsigned short)(r1 >> 48));
    w.v8 = bf2f((unsigned short)(v8w & 0xffff));
    return w;
}

__global__ __launch_bounds__(256) void displace_mul(
        unsigned short* __restrict__ pre, const unsigned short* __restrict__ a_sp,
        const float* __restrict__ spat, const float* __restrict__ disp) {
    __shared__ unsigned short img[128 * 136];
    int bc = blockIdx.x;
    int cc = bc & 127;
    const float* d = disp + cc * 6;
    int iy = (int)d[0], ix = (int)d[1];
    float w00 = d[2], w01 = d[3], w10 = d[4], w11 = d[5];
    float inv = 1.f / spat[bc];
    unsigned short* pb = pre + (size_t)bc * HWSZ;
    const unsigned short* ab = a_sp + (size_t)bc * HWSZ;
    int t = threadIdx.x;
    #pragma unroll
    for (int i = 0; i < 8; ++i) {
        int px = i * 2048 + t * 8;
        uint4 v = *(const uint4*)(pb + px);
        int y = px >> 7, xx = px & 127;
        *(uint4*)&img[y * 136 + xx] = v;
    }
    __syncthreads();
    int s = ix & 7;
    int ix8 = ix - s;
    int sh = (s & 3) * 16;
    bool s4 = s >= 4;
    for (int i = 0; i < 8; ++i) {
        int px = i * 2048 + t * 8;
        int y = px >> 7, x0 = px & 127;
        int yy0 = y + iy, yy1 = yy0 + 1;
        float wA0 = (yy0 >= 0 && yy0 < 128) ? w00 : 0.f;
        float wA1 = (yy0 >= 0 && yy0 < 128) ? w01 : 0.f;
        float wB0 = (yy1 >= 0 && yy1 < 128) ? w10 : 0.f;
        float wB1 = (yy1 >= 0 && yy1 < 128) ? w11 : 0.f;
        int yc0 = min(max(yy0, 0), 127), yc1 = min(max(yy1, 0), 127);
        int w0 = x0 + ix8;
        uint4 z = {0u, 0u, 0u, 0u};
        uint4 qa0 = (w0 >= 0 && w0 <= 120)         ? *(const uint4*)&img[yc0 * 136 + w0]     : z;
        uint4 qa1 = (w0 + 8 >= 0 && w0 + 8 <= 120) ? *(const uint4*)&img[yc0 * 136 + w0 + 8] : z;
        uint4 qb0 = (w0 >= 0 && w0 <= 120)         ? *(const uint4*)&img[yc1 * 136 + w0]     : z;
        uint4 qb1 = (w0 + 8 >= 0 && w0 + 8 <= 120) ? *(const uint4*)&img[yc1 * 136 + w0 + 8] : z;
        Win9 va = extract9(qa0, qa1, s4, sh);
        Win9 vb = extract9(qb0, qb1, s4, sh);
        float dv0 = wA0*va.v0 + wA1*va.v1 + wB0*vb.v0 + wB1*vb.v1;
        float dv1 = wA0*va.v1 + wA1*va.v2 + wB0*vb.v1 + wB1*vb.v2;
        float dv2 = wA0*va.v2 + wA1*va.v3 + wB0*vb.v2 + wB1*vb.v3;
        float dv3 = wA0*va.v3 + wA1*va.v4 + wB0*vb.v3 + wB1*vb.v4;
        float dv4 = wA0*va.v4 + wA1*va.v5 + wB0*vb.v4 + wB1*vb.v5;
        float dv5 = wA0*va.v5 + wA1*va.v6 + wB0*vb.v5 + wB1*vb.v6;
        float dv6 = wA0*va.v6 + wA1*va.v7 + wB0*vb.v6 + wB1*vb.v7;
        float dv7 = wA0*va.v7 + wA1*va.v8 + wB0*vb.v7 + wB1*vb.v8;
        uint4 av = *(const uint4*)(ab + px);
        unsigned int au[4] = {av.x, av.y, av.z, av.w};
        float a0 = bf2f((unsigned short)(au[0] & 0xffff)) * inv;
        float a1 = bf2f((unsigned short)(au[0] >> 16)) * inv;
        float a2 = bf2f((unsigned short)(au[1] & 0xffff)) * inv;
        float a3 = bf2f((unsigned short)(au[1] >> 16)) * inv;
        float a4 = bf2f((unsigned short)(au[2] & 0xffff)) * inv;
        float a5 = bf2f((unsigned short)(au[2] >> 16)) * inv;
        float a6 = bf2f((unsigned short)(au[3] & 0xffff)) * inv;
        float a7 = bf2f((unsigned short)(au[3] >> 16)) * inv;
        uint4 o;
        o.x = (unsigned int)f2bf(dv0 * a0) | ((unsigned int)f2bf(dv1 * a1) << 16);
        o.y = (unsigned int)f2bf(dv2 * a2) | ((unsigned int)f2bf(dv3 * a3) << 16);
        o.z = (unsigned int)f2bf(dv4 * a4) | ((unsigned int)f2bf(dv5 * a5) << 16);
        o.w = (unsigned int)f2bf(dv6 * a6) | ((unsigned int)f2bf(dv7 * a7) << 16);
        *(uint4*)(pb + px) = o;
    }
}

// ---------------- MFMA conv 128->64 + bias + skip -> skipS ----------------
__global__ __launch_bounds__(256) void conv_post_mfma(
        const unsigned short* __restrict__ m, const unsigned short* __restrict__ wP,
        const float* __restrict__ post_b, const float* __restrict__ x,
        unsigned short* __restrict__ skipS) {
    __shared__ unsigned short mT[128 * 128];  // byte = px*256 + ((c*2) ^ ((px&7)<<4))
    int t = threadIdx.x;
    int P0 = blockIdx.x * 128;
    int b = P0 >> 14, poff = P0 & 16383;
    int cl = t & 31, q = t >> 5;
    #pragma unroll
    for (int pass = 0; pass < 4; ++pass) {
        int c = cl + pass * 32;
        const unsigned short* mrow = m + ((size_t)b * CD + c) * HWSZ + poff;
        #pragma unroll
        for (int h = 0; h < 2; ++h) {
            int px0 = h * 64 + q * 8;
            uint4 v = *(const uint4*)(mrow + px0);
            unsigned int u[4] = {v.x, v.y, v.z, v.w};
            #pragma unroll
            for (int j = 0; j < 8; ++j) {
                unsigned short val = (unsigned short)((u[j >> 1] >> ((j & 1) * 16)) & 0xffff);
                int byteoff = (px0 + j) * 256 + ((c * 2) ^ (j << 4));
                *(unsigned short*)((char*)mT + byteoff) = val;
            }
        }
    }
    __syncthreads();
    int ln = t & 63, wv = t >> 6;
    int o0 = (wv >> 1) * 32;
    int ph = (wv & 1) * 64;
    short8x aw[2][4];
    #pragma unroll
    for (int oi = 0; oi < 2; ++oi)
        #pragma unroll
        for (int kk = 0; kk < 4; ++kk)
            aw[oi][kk] = *(const short8x*)(wP + (o0 + oi * 16 + (ln & 15)) * 128 + kk * 32 + (ln >> 4) * 8);
    floatx4 acc[2][4];
    #pragma unroll
    for (int oi = 0; oi < 2; ++oi)
        #pragma unroll
        for (int pi = 0; pi < 4; ++pi) acc[oi][pi] = floatx4{0.f, 0.f, 0.f, 0.f};
    #pragma unroll
    for (int kk = 0; kk < 4; ++kk)
        #pragma unroll
        for (int pi = 0; pi < 4; ++pi) {
            int px = ph + pi * 16 + (ln & 15);
            int cb = kk * 64 + (ln >> 4) * 16;
            short8x bf = *(const short8x*)((const char*)mT + px * 256 + (cb ^ ((px & 7) << 4)));
            #pragma unroll
            for (int oi = 0; oi < 2; ++oi)
                acc[oi][pi] = __builtin_amdgcn_mfma_f32_16x16x32_bf16(aw[oi][kk], bf, acc[oi][pi], 0, 0, 0);
        }
    #pragma unroll
    for (int oi = 0; oi < 2; ++oi) {
        float4 b4 = *(const float4*)(post_b + o0 + oi * 16 + (ln >> 4) * 4);
        float bb[4] = {b4.x, b4.y, b4.z, b4.w};
        #pragma unroll
        for (int pi = 0; pi < 4; ++pi) {
            int pxg = poff + ph + pi * 16 + (ln & 15);
            #pragma unroll
            for (int r = 0; r < 4; ++r) {
                int o = o0 + oi * 16 + (ln >> 4) * 4 + r;
                float val = acc[oi][pi][r] + bb[r] + x[((size_t)b * COUT + o) * HWSZ + pxg];
                skipS[((size_t)b * CD + o) * HWSZ + pxg] = f2bf(val);
            }
        }
    }
}

// ---------------- final BN + ReLU: skipS bf16 -> d_out fp32 ----------------
__global__ __launch_bounds__(256) void bn_relu_out(
        const unsigned short* __restrict__ skipS, float* __restrict__ out,
        const float* __restrict__ stats, const float* __restrict__ g,
        const float* __restrict__ bb) {
    const float N = 262144.f;
    int t = threadIdx.x;
    #pragma unroll
    for (int k = 0; k < 4; ++k) {
        size_t gidx = (size_t)blockIdx.x * 1024 + k * 256 + t;  // 8-elem index
        size_t e = gidx * 8;
        int b = (int)(e >> 20);
        int c = (int)(e >> 14) & 63;
        int px = (int)(e & 16383);
        float mean = stats[c * 2] / N;
        float rstd = rsqrtf(stats[c * 2 + 1] / N - mean * mean + BN_EPS);
        float gc = g[c], bbc = bb[c];
        uint4 v = *(const uint4*)(skipS + ((size_t)b * CD + c) * HWSZ + px);
        unsigned int u[4] = {v.x, v.y, v.z, v.w};
        float4 o0, o1;
        float* op[8] = {&o0.x, &o0.y, &o0.z, &o0.w, &o1.x, &o1.y, &o1.z, &o1.w};
        #pragma unroll
        for (int j = 0; j < 8; ++j) {
            float val = bf2f((unsigned short)((u[j >> 1] >> ((j & 1) * 16)) & 0xffff));
            *op[j] = fmaxf((val - mean) * rstd * gc + bbc, 0.f);
        }
        *(float4*)(out + e) = o0;
        *(float4*)(out + e + 4) = o1;
    }
}

extern "C" void kernel_launch(void* const* d_in, const int* in_sizes, int n_in,
                              void* d_out, int out_size, void* d_ws, size_t ws_size,
                              hipStream_t stream) {
    const float* x          = (const float*)d_in[0];
    const float* pre_w      = (const float*)d_in[1];
    const float* pre_b      = (const float*)d_in[2];
    const float* post_w     = (const float*)d_in[3];
    const float* post_b     = (const float*)d_in[4];
    const float* atten_w    = (const float*)d_in[5];
    const float* atten_b    = (const float*)d_in[6];
    const float* atten_bn_g = (const float*)d_in[7];
    const float* atten_bn_b = (const float*)d_in[8];
    const float* offsets    = (const float*)d_in[9];
    const float* bn_g       = (const float*)d_in[10];
    const float* bn_b       = (const float*)d_in[11];
    float* out = (float*)d_out;
    float* ws  = (float*)d_ws;

    if (ws_size < WS_TOTAL_BYTES) return;

    unsigned short* wAB = (unsigned short*)(ws + WS_WT1);
    unsigned short* wP  = (unsigned short*)(ws + WS_WTP);
    float* disp    = ws + WS_DISP;
    float* a_stats = ws + WS_ASTAT;
    float* o_stats = ws + WS_OSTAT;
    float* spat    = ws + WS_SPAT;
    unsigned short* big   = (unsigned short*)(ws + WS_BIG);  // out_pre -> m -> skipS
    unsigned short* a_buf = (unsigned short*)d_out;          // a_raw -> a_sp (bf16)

    hipMemsetAsync((void*)a_stats, 0, 384 * sizeof(float), stream);

    prep_kernel<<<97, 256, 0, stream>>>(pre_w, atten_w, post_w, offsets, ws);
    conv_pre_mfma<<<1024, 256, 0, stream>>>(x, wAB, pre_b, atten_b, big, a_buf);
    chan_stats_bf16<<<dim3(128, 16), 256, 0, stream>>>(a_buf, a_stats);
    bn_softplus<<<2048, 256, 0, stream>>>((unsigned int*)a_buf, a_stats, atten_bn_g, atten_bn_b, spat);
    displace_mul<<<2048, 256, 0, stream>>>(big, a_buf, spat, disp);
    conv_post_mfma<<<2048, 256, 0, stream>>>(big, wP, post_b, x, big);
    chan_stats_bf16<<<dim3(64, 16), 256, 0, stream>>>(big, o_stats);
    bn_relu_out<<<2048, 256, 0, stream>>>(big, out, o_stats, bn_g, bn_b);
}

// Round 8
// 175.287 us; speedup vs baseline: 1.1435x; 1.0275x over previous
//
#include <hip/hip_runtime.h>

#define HWSZ   16384
#define CIN    64
#define CD     128
#define COUT   64
#define BN_EPS 1e-5f

typedef __attribute__((ext_vector_type(8))) short short8x;
typedef __attribute__((ext_vector_type(4))) float floatx4;

// ws layout (float offsets):
//      0 : wAB bf16 [256][64]  (pre o0..127 | atten o128..255, [o][c] row-major)
//  16384 : wP  bf16 [64][128]
//  24576 : disp[128][6]
//  25344 : a_stats[256]
//  25600 : o_stats[128]
//  32768 : big region (64 MiB): out_pre -> m -> skipS (channel slots 0..63)
#define WS_WT1   0
#define WS_WTP   16384
#define WS_DISP  24576
#define WS_ASTAT 25344
#define WS_OSTAT 25600
#define WS_BIG   32768
#define WS_TOTAL_BYTES ((size_t)(32768 + 16777216) * 4)

__device__ __forceinline__ unsigned short f2bf(float f) {
    unsigned int u = __float_as_uint(f);
    u += 0x7fff + ((u >> 16) & 1);
    return (unsigned short)(u >> 16);
}
__device__ __forceinline__ float bf2f(unsigned short s) {
    return __uint_as_float(((unsigned int)s) << 16);
}
__device__ __forceinline__ float softplus_fast(float x) {
    return fmaxf(x, 0.f) + __logf(1.f + __expf(-fabsf(x)));
}
__device__ __forceinline__ float block_reduce(float v, float* sc) {
    #pragma unroll
    for (int off = 32; off >= 1; off >>= 1) v += __shfl_xor(v, off, 64);
    int wv = threadIdx.x >> 6, ln = threadIdx.x & 63;
    if (ln == 0) sc[wv] = v;
    __syncthreads();
    float r = (threadIdx.x < 4) ? sc[threadIdx.x] : 0.f;
    r += __shfl_xor(r, 1, 64);
    r += __shfl_xor(r, 2, 64);
    return r;
}

// ---------------- K0: weights->bf16 + displacement params ----------------
__global__ __launch_bounds__(256) void prep_kernel(
        const float* __restrict__ pre_w, const float* __restrict__ atten_w,
        const float* __restrict__ post_w, const float* __restrict__ offsets,
        float* __restrict__ ws) {
    int tid = blockIdx.x * 256 + threadIdx.x;
    unsigned short* wAB = (unsigned short*)(ws + WS_WT1);
    unsigned short* wP  = (unsigned short*)(ws + WS_WTP);
    float* disp = ws + WS_DISP;
    if (tid < 16384) {
        int o = tid >> 6, c = tid & 63;
        float v = (o < 128) ? pre_w[o * 64 + c] : atten_w[(o - 128) * 64 + c];
        wAB[tid] = f2bf(v);
    } else if (tid < 24576) {
        int k = tid - 16384;
        int o = k >> 7, c = k & 127;
        wP[k] = f2bf(post_w[o * 128 + c]);
    } else if (tid < 24704) {
        int c = tid - 24576;
        float dy = offsets[(c >> 2) * 2 + 0];
        float dx = offsets[(c >> 2) * 2 + 1];
        float fy = floorf(dy), fx = floorf(dx);
        float wy = dy - fy, wx = dx - fx;
        float* d = disp + c * 6;
        d[0] = fy; d[1] = fx;
        d[2] = (1.f - wy) * (1.f - wx);
        d[3] = (1.f - wy) * wx;
        d[4] = wy * (1.f - wx);
        d[5] = wy * wx;
    }
}

// ---------------- conv_pre helpers ----------------
__device__ __forceinline__ void pre_write_lds(unsigned short* wbuf, int c, int wv,
                                              const float4 ld[4]) {
    #pragma unroll
    for (int k = 0; k < 4; ++k) {
        int px = wv * 16 + k * 4;
        wbuf[(px + 0) * 72 + c] = f2bf(ld[k].x);
        wbuf[(px + 1) * 72 + c] = f2bf(ld[k].y);
        wbuf[(px + 2) * 72 + c] = f2bf(ld[k].z);
        wbuf[(px + 3) * 72 + c] = f2bf(ld[k].w);
    }
}

__device__ __forceinline__ void pre_compute_tile(
        const unsigned short* buf, int ln, int o0, int b, int ptile,
        const short8x wfrag[4][2], const float4 biasv[4],
        unsigned short* __restrict__ out_pre, unsigned short* __restrict__ a_out) {
    floatx4 acc[4][4];
    #pragma unroll
    for (int oi = 0; oi < 4; ++oi)
        #pragma unroll
        for (int pi = 0; pi < 4; ++pi)
            acc[oi][pi] = floatx4{biasv[oi].x, biasv[oi].y, biasv[oi].z, biasv[oi].w};
    #pragma unroll
    for (int kk = 0; kk < 2; ++kk)
        #pragma unroll
        for (int pi = 0; pi < 4; ++pi) {
            short8x xfrag = *(const short8x*)((const char*)buf +
                    (pi * 16 + (ln & 15)) * 144 + (kk * 32 + (ln >> 4) * 8) * 2);
            #pragma unroll
            for (int oi = 0; oi < 4; ++oi)
                acc[oi][pi] = __builtin_amdgcn_mfma_f32_16x16x32_bf16(
                        wfrag[oi][kk], xfrag, acc[oi][pi], 0, 0, 0);
        }
    #pragma unroll
    for (int oi = 0; oi < 4; ++oi) {
        int og = o0 + oi * 16;
        unsigned short* dst = (og < 128) ? out_pre : a_out;
        int ob = (og < 128) ? og : og - 128;
        #pragma unroll
        for (int pi = 0; pi < 4; ++pi) {
            int px = ptile + pi * 16 + (ln & 15);
            #pragma unroll
            for (int r = 0; r < 4; ++r) {
                int o = ob + (ln >> 4) * 4 + r;
                dst[((size_t)b * CD + o) * HWSZ + px] = f2bf(acc[oi][pi][r]);
            }
        }
    }
}

// ---------------- K1: MFMA conv1x1 (pre + atten), depth-2 pipelined ----------------
// block = 256 px (4 tiles x 64 px); loads for tile t+2 issued before compute(t).
__global__ __launch_bounds__(256) void conv_pre_mfma(
        const float* __restrict__ x, const unsigned short* __restrict__ wAB,
        const float* __restrict__ pre_b, const float* __restrict__ atten_b,
        unsigned short* __restrict__ out_pre, unsigned short* __restrict__ a_out) {
    __shared__ unsigned short xT[2][64 * 72];   // [px][c], row 72 bf16 = 144B
    int t = threadIdx.x;
    int wv = t >> 6, ln = t & 63;
    int b = blockIdx.x >> 6;
    int poff = (blockIdx.x & 63) << 8;          // 256-px super-tile
    const float* xg = x + (size_t)b * CIN * HWSZ + poff;
    int c = ln;

    int o0 = wv * 64;
    short8x wfrag[4][2];
    #pragma unroll
    for (int oi = 0; oi < 4; ++oi)
        #pragma unroll
        for (int kk = 0; kk < 2; ++kk) {
            int row = o0 + oi * 16 + (ln & 15);
            int kcol = kk * 32 + (ln >> 4) * 8;
            wfrag[oi][kk] = *(const short8x*)(wAB + row * 64 + kcol);
        }
    float4 biasv[4];
    #pragma unroll
    for (int oi = 0; oi < 4; ++oi) {
        int og = o0 + oi * 16;
        const float* bias = (og < 128) ? (pre_b + og) : (atten_b + og - 128);
        biasv[oi] = *(const float4*)(bias + (ln >> 4) * 4);
    }

    float4 lda[4], ldb[4];
    // prologue: tile0 -> lda -> buf0; tile1 -> lda (in flight across barrier)
    #pragma unroll
    for (int k = 0; k < 4; ++k)
        lda[k] = *(const float4*)(xg + (size_t)c * HWSZ + 0 * 64 + wv * 16 + k * 4);
    pre_write_lds(xT[0], c, wv, lda);
    #pragma unroll
    for (int k = 0; k < 4; ++k)
        lda[k] = *(const float4*)(xg + (size_t)c * HWSZ + 1 * 64 + wv * 16 + k * 4);
    __syncthreads();

    // tt=0: issue tile2 -> ldb; compute buf0; write buf1 <- lda(tile1)
    #pragma unroll
    for (int k = 0; k < 4; ++k)
        ldb[k] = *(const float4*)(xg + (size_t)c * HWSZ + 2 * 64 + wv * 16 + k * 4);
    pre_compute_tile(xT[0], ln, o0, b, poff + 0 * 64, wfrag, biasv, out_pre, a_out);
    pre_write_lds(xT[1], c, wv, lda);
    __syncthreads();

    // tt=1: issue tile3 -> lda; compute buf1; write buf0 <- ldb(tile2)
    #pragma unroll
    for (int k = 0; k < 4; ++k)
        lda[k] = *(const float4*)(xg + (size_t)c * HWSZ + 3 * 64 + wv * 16 + k * 4);
    pre_compute_tile(xT[1], ln, o0, b, poff + 1 * 64, wfrag, biasv, out_pre, a_out);
    pre_write_lds(xT[0], c, wv, ldb);
    __syncthreads();

    // tt=2: compute buf0; write buf1 <- lda(tile3)
    pre_compute_tile(xT[0], ln, o0, b, poff + 2 * 64, wfrag, biasv, out_pre, a_out);
    pre_write_lds(xT[1], c, wv, lda);
    __syncthreads();

    // tt=3: compute buf1
    pre_compute_tile(xT[1], ln, o0, b, poff + 3 * 64, wfrag, biasv, out_pre, a_out);
}

// ---------------- per-channel sum/sumsq over bf16 src ----------------
__global__ __launch_bounds__(256) void chan_stats_bf16(
        const unsigned short* __restrict__ src, float* __restrict__ stats) {
    __shared__ float sc1[8], sc2[8];
    int c = blockIdx.x, b = blockIdx.y;
    const unsigned short* base = src + ((size_t)b * CD + c) * HWSZ;
    int t = threadIdx.x;
    float sum = 0.f, sq = 0.f;
    #pragma unroll
    for (int i = 0; i < 8; ++i) {
        uint4 v = *(const uint4*)(base + i * 2048 + t * 8);
        unsigned int u[4] = {v.x, v.y, v.z, v.w};
        #pragma unroll
        for (int k = 0; k < 4; ++k) {
            float lo = bf2f((unsigned short)(u[k] & 0xffff));
            float hi = bf2f((unsigned short)(u[k] >> 16));
            sum += lo + hi;
            sq  += lo * lo + hi * hi;
        }
    }
    sum = block_reduce(sum, sc1);
    __syncthreads();
    sq = block_reduce(sq, sc2);
    if (t == 0) {
        atomicAdd(&stats[c * 2 + 0], sum);
        atomicAdd(&stats[c * 2 + 1], sq);
    }
}

// ---------------- fused: BN+softplus (LDS) + spat-reduce + displace + mul ----------------
struct Win9 { float v0,v1,v2,v3,v4,v5,v6,v7,v8; };
__device__ __forceinline__ Win9 extract9(uint4 qa, uint4 qb, bool s4, int sh) {
    unsigned long long A0 = ((unsigned long long)qa.y << 32) | qa.x;
    unsigned long long A1 = ((unsigned long long)qa.w << 32) | qa.z;
    unsigned long long A2 = ((unsigned long long)qb.y << 32) | qb.x;
    unsigned long long A3 = ((unsigned long long)qb.w << 32) | qb.z;
    unsigned long long B0 = s4 ? A1 : A0;
    unsigned long long B1 = s4 ? A2 : A1;
    unsigned long long B2 = s4 ? A3 : A2;
    unsigned long long r0 = sh ? ((B0 >> sh) | (B1 << (64 - sh))) : B0;
    unsigned long long r1 = sh ? ((B1 >> sh) | (B2 << (64 - sh))) : B1;
    unsigned int v8w = (unsigned int)(sh ? (B2 >> sh) : B2);
    Win9 w;
    w.v0 = bf2f((unsigned short)(r0 >>  0)); w.v1 = bf2f((unsigned short)(r0 >> 16));
    w.v2 = bf2f((unsigned short)(r0 >> 32)); w.v3 = bf2f((unsigned short)(r0 >> 48));
    w.v4 = bf2f((unsigned short)(r1 >>  0)); w.v5 = bf2f((unsigned short)(r1 >> 16));
    w.v6 = bf2f((unsigned short)(r1 >> 32)); w.v7 = bf2f((unsigned short)(r1 >> 48));
    w.v8 = bf2f((unsigned short)(v8w & 0xffff));
    return w;
}

__global__ __launch_bounds__(256) void displace_bnsp_mul(
        unsigned short* __restrict__ pre, const unsigned short* __restrict__ a_raw,
        const float* __restrict__ stats, const float* __restrict__ g,
        const float* __restrict__ bb, const float* __restrict__ disp) {
    __shared__ unsigned short img[128 * 136];   // pre channel image
    __shared__ unsigned short asp[16384];       // softplus(bn(a)) bf16
    __shared__ float sc[8];
    __shared__ float s_inv;
    int bc = blockIdx.x;
    int cc = bc & 127;
    const float* d = disp + cc * 6;
    int iy = (int)d[0], ix = (int)d[1];
    float w00 = d[2], w01 = d[3], w10 = d[4], w11 = d[5];
    const float N = 262144.f;
    float mean = stats[cc * 2] / N;
    float var  = stats[cc * 2 + 1] / N - mean * mean;
    float rstd = rsqrtf(var + BN_EPS);
    float scl = rstd * g[cc];
    float shf = bb[cc] - mean * scl;
    unsigned short* pb = pre + (size_t)bc * HWSZ;
    const unsigned short* ab = a_raw + (size_t)bc * HWSZ;
    int t = threadIdx.x;
    float lsum = 0.f;
    #pragma unroll
    for (int i = 0; i < 8; ++i) {
        int px = i * 2048 + t * 8;
        // pre image -> img
        uint4 v = *(const uint4*)(pb + px);
        int y = px >> 7, xx = px & 127;
        *(uint4*)&img[y * 136 + xx] = v;
        // a_raw -> softplus(bn) -> asp + spatial sum
        uint4 av = *(const uint4*)(ab + px);
        unsigned int au[4] = {av.x, av.y, av.z, av.w};
        uint4 o;
        unsigned int* ou = (unsigned int*)&o;
        #pragma unroll
        for (int k = 0; k < 4; ++k) {
            float lo = softplus_fast(bf2f((unsigned short)(au[k] & 0xffff)) * scl + shf);
            float hi = softplus_fast(bf2f((unsigned short)(au[k] >> 16))    * scl + shf);
            lsum += lo + hi;
            ou[k] = (unsigned int)f2bf(lo) | ((unsigned int)f2bf(hi) << 16);
        }
        *(uint4*)&asp[px] = o;
    }
    lsum = block_reduce(lsum, sc);      // internal syncthreads covers LDS writes
    if (t == 0) s_inv = 1.f / lsum;
    __syncthreads();
    float inv = s_inv;
    int s = ix & 7;
    int ix8 = ix - s;
    int sh = (s & 3) * 16;
    bool s4 = s >= 4;
    for (int i = 0; i < 8; ++i) {
        int px = i * 2048 + t * 8;
        int y = px >> 7, x0 = px & 127;
        int yy0 = y + iy, yy1 = yy0 + 1;
        float wA0 = (yy0 >= 0 && yy0 < 128) ? w00 : 0.f;
        float wA1 = (yy0 >= 0 && yy0 < 128) ? w01 : 0.f;
        float wB0 = (yy1 >= 0 && yy1 < 128) ? w10 : 0.f;
        float wB1 = (yy1 >= 0 && yy1 < 128) ? w11 : 0.f;
        int yc0 = min(max(yy0, 0), 127), yc1 = min(max(yy1, 0), 127);
        int w0 = x0 + ix8;
        uint4 z = {0u, 0u, 0u, 0u};
        uint4 qa0 = (w0 >= 0 && w0 <= 120)         ? *(const uint4*)&img[yc0 * 136 + w0]     : z;
        uint4 qa1 = (w0 + 8 >= 0 && w0 + 8 <= 120) ? *(const uint4*)&img[yc0 * 136 + w0 + 8] : z;
        uint4 qb0 = (w0 >= 0 && w0 <= 120)         ? *(const uint4*)&img[yc1 * 136 + w0]     : z;
        uint4 qb1 = (w0 + 8 >= 0 && w0 + 8 <= 120) ? *(const uint4*)&img[yc1 * 136 + w0 + 8] : z;
        Win9 va = extract9(qa0, qa1, s4, sh);
        Win9 vb = extract9(qb0, qb1, s4, sh);
        float dv0 = wA0*va.v0 + wA1*va.v1 + wB0*vb.v0 + wB1*vb.v1;
        float dv1 = wA0*va.v1 + wA1*va.v2 + wB0*vb.v1 + wB1*vb.v2;
        float dv2 = wA0*va.v2 + wA1*va.v3 + wB0*vb.v2 + wB1*vb.v3;
        float dv3 = wA0*va.v3 + wA1*va.v4 + wB0*vb.v3 + wB1*vb.v4;
        float dv4 = wA0*va.v4 + wA1*va.v5 + wB0*vb.v4 + wB1*vb.v5;
        float dv5 = wA0*va.v5 + wA1*va.v6 + wB0*vb.v5 + wB1*vb.v6;
        float dv6 = wA0*va.v6 + wA1*va.v7 + wB0*vb.v6 + wB1*vb.v7;
        float dv7 = wA0*va.v7 + wA1*va.v8 + wB0*vb.v7 + wB1*vb.v8;
        uint4 av = *(const uint4*)&asp[px];
        unsigned int au[4] = {av.x, av.y, av.z, av.w};
        float a0 = bf2f((unsigned short)(au[0] & 0xffff)) * inv;
        float a1 = bf2f((unsigned short)(au[0] >> 16)) * inv;
        float a2 = bf2f((unsigned short)(au[1] & 0xffff)) * inv;
        float a3 = bf2f((unsigned short)(au[1] >> 16)) * inv;
        float a4 = bf2f((unsigned short)(au[2] & 0xffff)) * inv;
        float a5 = bf2f((unsigned short)(au[2] >> 16)) * inv;
        float a6 = bf2f((unsigned short)(au[3] & 0xffff)) * inv;
        float a7 = bf2f((unsigned short)(au[3] >> 16)) * inv;
        uint4 o;
        o.x = (unsigned int)f2bf(dv0 * a0) | ((unsigned int)f2bf(dv1 * a1) << 16);
        o.y = (unsigned int)f2bf(dv2 * a2) | ((unsigned int)f2bf(dv3 * a3) << 16);
        o.z = (unsigned int)f2bf(dv4 * a4) | ((unsigned int)f2bf(dv5 * a5) << 16);
        o.w = (unsigned int)f2bf(dv6 * a6) | ((unsigned int)f2bf(dv7 * a7) << 16);
        *(uint4*)(pb + px) = o;
    }
}

// ---------------- MFMA conv 128->64 + bias + skip -> skipS ----------------
__global__ __launch_bounds__(256) void conv_post_mfma(
        const unsigned short* __restrict__ m, const unsigned short* __restrict__ wP,
        const float* __restrict__ post_b, const float* __restrict__ x,
        unsigned short* __restrict__ skipS) {
    __shared__ unsigned short mT[128 * 128];  // byte = px*256 + ((c*2) ^ ((px&7)<<4))
    int t = threadIdx.x;
    int P0 = blockIdx.x * 128;
    int b = P0 >> 14, poff = P0 & 16383;
    int cl = t & 31, q = t >> 5;
    #pragma unroll
    for (int pass = 0; pass < 4; ++pass) {
        int c = cl + pass * 32;
        const unsigned short* mrow = m + ((size_t)b * CD + c) * HWSZ + poff;
        #pragma unroll
        for (int h = 0; h < 2; ++h) {
            int px0 = h * 64 + q * 8;
            uint4 v = *(const uint4*)(mrow + px0);
            unsigned int u[4] = {v.x, v.y, v.z, v.w};
            #pragma unroll
            for (int j = 0; j < 8; ++j) {
                unsigned short val = (unsigned short)((u[j >> 1] >> ((j & 1) * 16)) & 0xffff);
                int byteoff = (px0 + j) * 256 + ((c * 2) ^ (j << 4));
                *(unsigned short*)((char*)mT + byteoff) = val;
            }
        }
    }
    __syncthreads();
    int ln = t & 63, wv = t >> 6;
    int o0 = (wv >> 1) * 32;
    int ph = (wv & 1) * 64;
    short8x aw[2][4];
    #pragma unroll
    for (int oi = 0; oi < 2; ++oi)
        #pragma unroll
        for (int kk = 0; kk < 4; ++kk)
            aw[oi][kk] = *(const short8x*)(wP + (o0 + oi * 16 + (ln & 15)) * 128 + kk * 32 + (ln >> 4) * 8);
    floatx4 acc[2][4];
    #pragma unroll
    for (int oi = 0; oi < 2; ++oi)
        #pragma unroll
        for (int pi = 0; pi < 4; ++pi) acc[oi][pi] = floatx4{0.f, 0.f, 0.f, 0.f};
    #pragma unroll
    for (int kk = 0; kk < 4; ++kk)
        #pragma unroll
        for (int pi = 0; pi < 4; ++pi) {
            int px = ph + pi * 16 + (ln & 15);
            int cb = kk * 64 + (ln >> 4) * 16;
            short8x bf = *(const short8x*)((const char*)mT + px * 256 + (cb ^ ((px & 7) << 4)));
            #pragma unroll
            for (int oi = 0; oi < 2; ++oi)
                acc[oi][pi] = __builtin_amdgcn_mfma_f32_16x16x32_bf16(aw[oi][kk], bf, acc[oi][pi], 0, 0, 0);
        }
    #pragma unroll
    for (int oi = 0; oi < 2; ++oi) {
        float4 b4 = *(const float4*)(post_b + o0 + oi * 16 + (ln >> 4) * 4);
        float bb[4] = {b4.x, b4.y, b4.z, b4.w};
        #pragma unroll
        for (int pi = 0; pi < 4; ++pi) {
            int pxg = poff + ph + pi * 16 + (ln & 15);
            #pragma unroll
            for (int r = 0; r < 4; ++r) {
                int o = o0 + oi * 16 + (ln >> 4) * 4 + r;
                float val = acc[oi][pi][r] + bb[r] + x[((size_t)b * COUT + o) * HWSZ + pxg];
                skipS[((size_t)b * CD + o) * HWSZ + pxg] = f2bf(val);
            }
        }
    }
}

// ---------------- final BN + ReLU: skipS bf16 -> d_out fp32 ----------------
__global__ __launch_bounds__(256) void bn_relu_out(
        const unsigned short* __restrict__ skipS, float* __restrict__ out,
        const float* __restrict__ stats, const float* __restrict__ g,
        const float* __restrict__ bb) {
    const float N = 262144.f;
    int t = threadIdx.x;
    #pragma unroll
    for (int k = 0; k < 4; ++k) {
        size_t gidx = (size_t)blockIdx.x * 1024 + k * 256 + t;  // 8-elem index
        size_t e = gidx * 8;
        int b = (int)(e >> 20);
        int c = (int)(e >> 14) & 63;
        int px = (int)(e & 16383);
        float mean = stats[c * 2] / N;
        float rstd = rsqrtf(stats[c * 2 + 1] / N - mean * mean + BN_EPS);
        float gc = g[c], bbc = bb[c];
        uint4 v = *(const uint4*)(skipS + ((size_t)b * CD + c) * HWSZ + px);
        unsigned int u[4] = {v.x, v.y, v.z, v.w};
        float4 o0, o1;
        float* op[8] = {&o0.x, &o0.y, &o0.z, &o0.w, &o1.x, &o1.y, &o1.z, &o1.w};
        #pragma unroll
        for (int j = 0; j < 8; ++j) {
            float val = bf2f((unsigned short)((u[j >> 1] >> ((j & 1) * 16)) & 0xffff));
            *op[j] = fmaxf((val - mean) * rstd * gc + bbc, 0.f);
        }
        *(float4*)(out + e) = o0;
        *(float4*)(out + e + 4) = o1;
    }
}

extern "C" void kernel_launch(void* const* d_in, const int* in_sizes, int n_in,
                              void* d_out, int out_size, void* d_ws, size_t ws_size,
                              hipStream_t stream) {
    const float* x          = (const float*)d_in[0];
    const float* pre_w      = (const float*)d_in[1];
    const float* pre_b      = (const float*)d_in[2];
    const float* post_w     = (const float*)d_in[3];
    const float* post_b     = (const float*)d_in[4];
    const float* atten_w    = (const float*)d_in[5];
    const float* atten_b    = (const float*)d_in[6];
    const float* atten_bn_g = (const float*)d_in[7];
    const float* atten_bn_b = (const float*)d_in[8];
    const float* offsets    = (const float*)d_in[9];
    const float* bn_g       = (const float*)d_in[10];
    const float* bn_b       = (const float*)d_in[11];
    float* out = (float*)d_out;
    float* ws  = (float*)d_ws;

    if (ws_size < WS_TOTAL_BYTES) return;

    unsigned short* wAB = (unsigned short*)(ws + WS_WT1);
    unsigned short* wP  = (unsigned short*)(ws + WS_WTP);
    float* disp    = ws + WS_DISP;
    float* a_stats = ws + WS_ASTAT;
    float* o_stats = ws + WS_OSTAT;
    unsigned short* big   = (unsigned short*)(ws + WS_BIG);  // out_pre -> m -> skipS
    unsigned short* a_buf = (unsigned short*)d_out;          // a_raw (bf16)

    hipMemsetAsync((void*)a_stats, 0, 384 * sizeof(float), stream);

    prep_kernel<<<97, 256, 0, stream>>>(pre_w, atten_w, post_w, offsets, ws);
    conv_pre_mfma<<<1024, 256, 0, stream>>>(x, wAB, pre_b, atten_b, big, a_buf);
    chan_stats_bf16<<<dim3(128, 16), 256, 0, stream>>>(a_buf, a_stats);
    displace_bnsp_mul<<<2048, 256, 0, stream>>>(big, a_buf, a_stats, atten_bn_g, atten_bn_b, disp);
    conv_post_mfma<<<2048, 256, 0, stream>>>(big, wP, post_b, x, big);
    chan_stats_bf16<<<dim3(64, 16), 256, 0, stream>>>(big, o_stats);
    bn_relu_out<<<2048, 256, 0, stream>>>(big, out, o_stats, bn_g, bn_b);
}

// Round 9
// 161.984 us; speedup vs baseline: 1.2374x; 1.0821x over previous
//
#include <hip/hip_runtime.h>

#define HWSZ   16384
#define CIN    64
#define CD     128
#define COUT   64
#define BN_EPS 1e-5f

typedef __attribute__((ext_vector_type(8))) short short8x;
typedef __attribute__((ext_vector_type(4))) float floatx4;

// ws layout (float offsets):
//      0 : wAB bf16 [256][64]  (pre o0..127 | atten o128..255, [o][c] row-major)
//  16384 : wP  bf16 [64][128]
//  24576 : disp[128][6]
//  25344 : a_stats[256]
//  25600 : o_stats[128]
//  32768 : big region (64 MiB): out_pre -> m -> skipS (channel slots 0..63)
#define WS_WT1   0
#define WS_WTP   16384
#define WS_DISP  24576
#define WS_ASTAT 25344
#define WS_OSTAT 25600
#define WS_BIG   32768
#define WS_TOTAL_BYTES ((size_t)(32768 + 16777216) * 4)

__device__ __forceinline__ unsigned short f2bf(float f) {
    unsigned int u = __float_as_uint(f);
    u += 0x7fff + ((u >> 16) & 1);
    return (unsigned short)(u >> 16);
}
__device__ __forceinline__ float bf2f(unsigned short s) {
    return __uint_as_float(((unsigned int)s) << 16);
}
__device__ __forceinline__ float softplus_fast(float x) {
    return fmaxf(x, 0.f) + __logf(1.f + __expf(-fabsf(x)));
}
__device__ __forceinline__ float block_reduce(float v, float* sc) {
    #pragma unroll
    for (int off = 32; off >= 1; off >>= 1) v += __shfl_xor(v, off, 64);
    int wv = threadIdx.x >> 6, ln = threadIdx.x & 63;
    if (ln == 0) sc[wv] = v;
    __syncthreads();
    float r = (threadIdx.x < 4) ? sc[threadIdx.x] : 0.f;
    r += __shfl_xor(r, 1, 64);
    r += __shfl_xor(r, 2, 64);
    return r;
}

// ---------------- K0: weights->bf16 + displacement params ----------------
__global__ __launch_bounds__(256) void prep_kernel(
        const float* __restrict__ pre_w, const float* __restrict__ atten_w,
        const float* __restrict__ post_w, const float* __restrict__ offsets,
        float* __restrict__ ws) {
    int tid = blockIdx.x * 256 + threadIdx.x;
    unsigned short* wAB = (unsigned short*)(ws + WS_WT1);
    unsigned short* wP  = (unsigned short*)(ws + WS_WTP);
    float* disp = ws + WS_DISP;
    if (tid < 16384) {
        int o = tid >> 6, c = tid & 63;
        float v = (o < 128) ? pre_w[o * 64 + c] : atten_w[(o - 128) * 64 + c];
        wAB[tid] = f2bf(v);
    } else if (tid < 24576) {
        int k = tid - 16384;
        int o = k >> 7, c = k & 127;
        wP[k] = f2bf(post_w[o * 128 + c]);
    } else if (tid < 24704) {
        int c = tid - 24576;
        float dy = offsets[(c >> 2) * 2 + 0];
        float dx = offsets[(c >> 2) * 2 + 1];
        float fy = floorf(dy), fx = floorf(dx);
        float wy = dy - fy, wx = dx - fx;
        float* d = disp + c * 6;
        d[0] = fy; d[1] = fx;
        d[2] = (1.f - wy) * (1.f - wx);
        d[3] = (1.f - wy) * wx;
        d[4] = wy * (1.f - wx);
        d[5] = wy * wx;
    }
}

// ---------------- conv_pre helpers ----------------
__device__ __forceinline__ void pre_write_lds(unsigned short* wbuf, int c, int wv,
                                              const float4 ld[4]) {
    #pragma unroll
    for (int k = 0; k < 4; ++k) {
        int px = wv * 16 + k * 4;
        wbuf[(px + 0) * 72 + c] = f2bf(ld[k].x);
        wbuf[(px + 1) * 72 + c] = f2bf(ld[k].y);
        wbuf[(px + 2) * 72 + c] = f2bf(ld[k].z);
        wbuf[(px + 3) * 72 + c] = f2bf(ld[k].w);
    }
}

__device__ __forceinline__ void pre_compute_tile(
        const unsigned short* buf, int ln, int o0, int b, int ptile,
        const short8x wfrag[4][2], const float4 biasv[4],
        unsigned short* __restrict__ out_pre, unsigned short* __restrict__ a_out) {
    floatx4 acc[4][4];
    #pragma unroll
    for (int oi = 0; oi < 4; ++oi)
        #pragma unroll
        for (int pi = 0; pi < 4; ++pi)
            acc[oi][pi] = floatx4{biasv[oi].x, biasv[oi].y, biasv[oi].z, biasv[oi].w};
    #pragma unroll
    for (int kk = 0; kk < 2; ++kk)
        #pragma unroll
        for (int pi = 0; pi < 4; ++pi) {
            short8x xfrag = *(const short8x*)((const char*)buf +
                    (pi * 16 + (ln & 15)) * 144 + (kk * 32 + (ln >> 4) * 8) * 2);
            #pragma unroll
            for (int oi = 0; oi < 4; ++oi)
                acc[oi][pi] = __builtin_amdgcn_mfma_f32_16x16x32_bf16(
                        wfrag[oi][kk], xfrag, acc[oi][pi], 0, 0, 0);
        }
    #pragma unroll
    for (int oi = 0; oi < 4; ++oi) {
        int og = o0 + oi * 16;
        unsigned short* dst = (og < 128) ? out_pre : a_out;
        int ob = (og < 128) ? og : og - 128;
        #pragma unroll
        for (int pi = 0; pi < 4; ++pi) {
            int px = ptile + pi * 16 + (ln & 15);
            #pragma unroll
            for (int r = 0; r < 4; ++r) {
                int o = ob + (ln >> 4) * 4 + r;
                dst[((size_t)b * CD + o) * HWSZ + px] = f2bf(acc[oi][pi][r]);
            }
        }
    }
}

// ---------------- K1: MFMA conv1x1 (pre + atten), depth-2 pipelined ----------------
__global__ __launch_bounds__(256) void conv_pre_mfma(
        const float* __restrict__ x, const unsigned short* __restrict__ wAB,
        const float* __restrict__ pre_b, const float* __restrict__ atten_b,
        unsigned short* __restrict__ out_pre, unsigned short* __restrict__ a_out) {
    __shared__ unsigned short xT[2][64 * 72];   // [px][c], row 72 bf16 = 144B
    int t = threadIdx.x;
    int wv = t >> 6, ln = t & 63;
    int b = blockIdx.x >> 6;
    int poff = (blockIdx.x & 63) << 8;          // 256-px super-tile
    const float* xg = x + (size_t)b * CIN * HWSZ + poff;
    int c = ln;

    int o0 = wv * 64;
    short8x wfrag[4][2];
    #pragma unroll
    for (int oi = 0; oi < 4; ++oi)
        #pragma unroll
        for (int kk = 0; kk < 2; ++kk) {
            int row = o0 + oi * 16 + (ln & 15);
            int kcol = kk * 32 + (ln >> 4) * 8;
            wfrag[oi][kk] = *(const short8x*)(wAB + row * 64 + kcol);
        }
    float4 biasv[4];
    #pragma unroll
    for (int oi = 0; oi < 4; ++oi) {
        int og = o0 + oi * 16;
        const float* bias = (og < 128) ? (pre_b + og) : (atten_b + og - 128);
        biasv[oi] = *(const float4*)(bias + (ln >> 4) * 4);
    }

    float4 lda[4], ldb[4];
    #pragma unroll
    for (int k = 0; k < 4; ++k)
        lda[k] = *(const float4*)(xg + (size_t)c * HWSZ + 0 * 64 + wv * 16 + k * 4);
    pre_write_lds(xT[0], c, wv, lda);
    #pragma unroll
    for (int k = 0; k < 4; ++k)
        lda[k] = *(const float4*)(xg + (size_t)c * HWSZ + 1 * 64 + wv * 16 + k * 4);
    __syncthreads();

    #pragma unroll
    for (int k = 0; k < 4; ++k)
        ldb[k] = *(const float4*)(xg + (size_t)c * HWSZ + 2 * 64 + wv * 16 + k * 4);
    pre_compute_tile(xT[0], ln, o0, b, poff + 0 * 64, wfrag, biasv, out_pre, a_out);
    pre_write_lds(xT[1], c, wv, lda);
    __syncthreads();

    #pragma unroll
    for (int k = 0; k < 4; ++k)
        lda[k] = *(const float4*)(xg + (size_t)c * HWSZ + 3 * 64 + wv * 16 + k * 4);
    pre_compute_tile(xT[1], ln, o0, b, poff + 1 * 64, wfrag, biasv, out_pre, a_out);
    pre_write_lds(xT[0], c, wv, ldb);
    __syncthreads();

    pre_compute_tile(xT[0], ln, o0, b, poff + 2 * 64, wfrag, biasv, out_pre, a_out);
    pre_write_lds(xT[1], c, wv, lda);
    __syncthreads();

    pre_compute_tile(xT[1], ln, o0, b, poff + 3 * 64, wfrag, biasv, out_pre, a_out);
}

// ---------------- per-channel sum/sumsq over bf16 src ----------------
__global__ __launch_bounds__(256) void chan_stats_bf16(
        const unsigned short* __restrict__ src, float* __restrict__ stats) {
    __shared__ float sc1[8], sc2[8];
    int c = blockIdx.x, b = blockIdx.y;
    const unsigned short* base = src + ((size_t)b * CD + c) * HWSZ;
    int t = threadIdx.x;
    float sum = 0.f, sq = 0.f;
    #pragma unroll
    for (int i = 0; i < 8; ++i) {
        uint4 v = *(const uint4*)(base + i * 2048 + t * 8);
        unsigned int u[4] = {v.x, v.y, v.z, v.w};
        #pragma unroll
        for (int k = 0; k < 4; ++k) {
            float lo = bf2f((unsigned short)(u[k] & 0xffff));
            float hi = bf2f((unsigned short)(u[k] >> 16));
            sum += lo + hi;
            sq  += lo * lo + hi * hi;
        }
    }
    sum = block_reduce(sum, sc1);
    __syncthreads();
    sq = block_reduce(sq, sc2);
    if (t == 0) {
        atomicAdd(&stats[c * 2 + 0], sum);
        atomicAdd(&stats[c * 2 + 1], sq);
    }
}

// ---------------- fused: BN+softplus (regs) + spat-reduce + displace + mul ----------------
struct Win9 { float v0,v1,v2,v3,v4,v5,v6,v7,v8; };
__device__ __forceinline__ Win9 extract9(uint4 qa, uint4 qb, bool s4, int sh) {
    unsigned long long A0 = ((unsigned long long)qa.y << 32) | qa.x;
    unsigned long long A1 = ((unsigned long long)qa.w << 32) | qa.z;
    unsigned long long A2 = ((unsigned long long)qb.y << 32) | qb.x;
    unsigned long long A3 = ((unsigned long long)qb.w << 32) | qb.z;
    unsigned long long B0 = s4 ? A1 : A0;
    unsigned long long B1 = s4 ? A2 : A1;
    unsigned long long B2 = s4 ? A3 : A2;
    unsigned long long r0 = sh ? ((B0 >> sh) | (B1 << (64 - sh))) : B0;
    unsigned long long r1 = sh ? ((B1 >> sh) | (B2 << (64 - sh))) : B1;
    unsigned int v8w = (unsigned int)(sh ? (B2 >> sh) : B2);
    Win9 w;
    w.v0 = bf2f((unsigned short)(r0 >>  0)); w.v1 = bf2f((unsigned short)(r0 >> 16));
    w.v2 = bf2f((unsigned short)(r0 >> 32)); w.v3 = bf2f((unsigned short)(r0 >> 48));
    w.v4 = bf2f((unsigned short)(r1 >>  0)); w.v5 = bf2f((unsigned short)(r1 >> 16));
    w.v6 = bf2f((unsigned short)(r1 >> 32)); w.v7 = bf2f((unsigned short)(r1 >> 48));
    w.v8 = bf2f((unsigned short)(v8w & 0xffff));
    return w;
}

__global__ __launch_bounds__(256) void displace_bnsp_mul(
        unsigned short* __restrict__ pre, const unsigned short* __restrict__ a_raw,
        const float* __restrict__ stats, const float* __restrict__ g,
        const float* __restrict__ bb, const float* __restrict__ disp) {
    __shared__ unsigned short img[128 * 136];   // pre channel image (34.8 KB)
    __shared__ float sc[8];
    __shared__ float s_inv;
    int bc = blockIdx.x;
    int cc = bc & 127;
    const float* d = disp + cc * 6;
    int iy = (int)d[0], ix = (int)d[1];
    float w00 = d[2], w01 = d[3], w10 = d[4], w11 = d[5];
    const float N = 262144.f;
    float mean = stats[cc * 2] / N;
    float var  = stats[cc * 2 + 1] / N - mean * mean;
    float rstd = rsqrtf(var + BN_EPS);
    float scl = rstd * g[cc];
    float shf = bb[cc] - mean * scl;
    unsigned short* pb = pre + (size_t)bc * HWSZ;
    const unsigned short* ab = a_raw + (size_t)bc * HWSZ;
    int t = threadIdx.x;
    uint4 aspr[8];                  // softplus(bn(a)) packed bf16, REGISTERS
    float lsum = 0.f;
    #pragma unroll
    for (int i = 0; i < 8; ++i) {
        int px = i * 2048 + t * 8;
        uint4 v = *(const uint4*)(pb + px);
        int y = px >> 7, xx = px & 127;
        *(uint4*)&img[y * 136 + xx] = v;
        uint4 av = *(const uint4*)(ab + px);
        unsigned int au[4] = {av.x, av.y, av.z, av.w};
        unsigned int ou[4];
        #pragma unroll
        for (int k = 0; k < 4; ++k) {
            float lo = softplus_fast(bf2f((unsigned short)(au[k] & 0xffff)) * scl + shf);
            float hi = softplus_fast(bf2f((unsigned short)(au[k] >> 16))    * scl + shf);
            lsum += lo + hi;
            ou[k] = (unsigned int)f2bf(lo) | ((unsigned int)f2bf(hi) << 16);
        }
        aspr[i] = uint4{ou[0], ou[1], ou[2], ou[3]};
    }
    lsum = block_reduce(lsum, sc);      // internal syncthreads covers img writes
    if (t == 0) s_inv = 1.f / lsum;
    __syncthreads();
    float inv = s_inv;
    int s = ix & 7;
    int ix8 = ix - s;
    int sh = (s & 3) * 16;
    bool s4 = s >= 4;
    #pragma unroll
    for (int i = 0; i < 8; ++i) {
        int px = i * 2048 + t * 8;
        int y = px >> 7, x0 = px & 127;
        int yy0 = y + iy, yy1 = yy0 + 1;
        float wA0 = (yy0 >= 0 && yy0 < 128) ? w00 : 0.f;
        float wA1 = (yy0 >= 0 && yy0 < 128) ? w01 : 0.f;
        float wB0 = (yy1 >= 0 && yy1 < 128) ? w10 : 0.f;
        float wB1 = (yy1 >= 0 && yy1 < 128) ? w11 : 0.f;
        int yc0 = min(max(yy0, 0), 127), yc1 = min(max(yy1, 0), 127);
        int w0 = x0 + ix8;
        uint4 z = {0u, 0u, 0u, 0u};
        uint4 qa0 = (w0 >= 0 && w0 <= 120)         ? *(const uint4*)&img[yc0 * 136 + w0]     : z;
        uint4 qa1 = (w0 + 8 >= 0 && w0 + 8 <= 120) ? *(const uint4*)&img[yc0 * 136 + w0 + 8] : z;
        uint4 qb0 = (w0 >= 0 && w0 <= 120)         ? *(const uint4*)&img[yc1 * 136 + w0]     : z;
        uint4 qb1 = (w0 + 8 >= 0 && w0 + 8 <= 120) ? *(const uint4*)&img[yc1 * 136 + w0 + 8] : z;
        Win9 va = extract9(qa0, qa1, s4, sh);
        Win9 vb = extract9(qb0, qb1, s4, sh);
        float dv0 = wA0*va.v0 + wA1*va.v1 + wB0*vb.v0 + wB1*vb.v1;
        float dv1 = wA0*va.v1 + wA1*va.v2 + wB0*vb.v1 + wB1*vb.v2;
        float dv2 = wA0*va.v2 + wA1*va.v3 + wB0*vb.v2 + wB1*vb.v3;
        float dv3 = wA0*va.v3 + wA1*va.v4 + wB0*vb.v3 + wB1*vb.v4;
        float dv4 = wA0*va.v4 + wA1*va.v5 + wB0*vb.v4 + wB1*vb.v5;
        float dv5 = wA0*va.v5 + wA1*va.v6 + wB0*vb.v5 + wB1*vb.v6;
        float dv6 = wA0*va.v6 + wA1*va.v7 + wB0*vb.v6 + wB1*vb.v7;
        float dv7 = wA0*va.v7 + wA1*va.v8 + wB0*vb.v7 + wB1*vb.v8;
        unsigned int au[4] = {aspr[i].x, aspr[i].y, aspr[i].z, aspr[i].w};
        float a0 = bf2f((unsigned short)(au[0] & 0xffff)) * inv;
        float a1 = bf2f((unsigned short)(au[0] >> 16)) * inv;
        float a2 = bf2f((unsigned short)(au[1] & 0xffff)) * inv;
        float a3 = bf2f((unsigned short)(au[1] >> 16)) * inv;
        float a4 = bf2f((unsigned short)(au[2] & 0xffff)) * inv;
        float a5 = bf2f((unsigned short)(au[2] >> 16)) * inv;
        float a6 = bf2f((unsigned short)(au[3] & 0xffff)) * inv;
        float a7 = bf2f((unsigned short)(au[3] >> 16)) * inv;
        uint4 o;
        o.x = (unsigned int)f2bf(dv0 * a0) | ((unsigned int)f2bf(dv1 * a1) << 16);
        o.y = (unsigned int)f2bf(dv2 * a2) | ((unsigned int)f2bf(dv3 * a3) << 16);
        o.z = (unsigned int)f2bf(dv4 * a4) | ((unsigned int)f2bf(dv5 * a5) << 16);
        o.w = (unsigned int)f2bf(dv6 * a6) | ((unsigned int)f2bf(dv7 * a7) << 16);
        *(uint4*)(pb + px) = o;
    }
}

// ---------------- MFMA conv 128->64 + bias + skip -> skipS ----------------
__global__ __launch_bounds__(256) void conv_post_mfma(
        const unsigned short* __restrict__ m, const unsigned short* __restrict__ wP,
        const float* __restrict__ post_b, const float* __restrict__ x,
        unsigned short* __restrict__ skipS) {
    __shared__ unsigned short mT[128 * 128];  // byte = px*256 + ((c*2) ^ ((px&7)<<4))
    int t = threadIdx.x;
    int P0 = blockIdx.x * 128;
    int b = P0 >> 14, poff = P0 & 16383;
    int cl = t & 31, q = t >> 5;
    #pragma unroll
    for (int pass = 0; pass < 4; ++pass) {
        int c = cl + pass * 32;
        const unsigned short* mrow = m + ((size_t)b * CD + c) * HWSZ + poff;
        #pragma unroll
        for (int h = 0; h < 2; ++h) {
            int px0 = h * 64 + q * 8;
            uint4 v = *(const uint4*)(mrow + px0);
            unsigned int u[4] = {v.x, v.y, v.z, v.w};
            #pragma unroll
            for (int j = 0; j < 8; ++j) {
                unsigned short val = (unsigned short)((u[j >> 1] >> ((j & 1) * 16)) & 0xffff);
                int byteoff = (px0 + j) * 256 + ((c * 2) ^ (j << 4));
                *(unsigned short*)((char*)mT + byteoff) = val;
            }
        }
    }
    __syncthreads();
    int ln = t & 63, wv = t >> 6;
    int o0 = (wv >> 1) * 32;
    int ph = (wv & 1) * 64;
    short8x aw[2][4];
    #pragma unroll
    for (int oi = 0; oi < 2; ++oi)
        #pragma unroll
        for (int kk = 0; kk < 4; ++kk)
            aw[oi][kk] = *(const short8x*)(wP + (o0 + oi * 16 + (ln & 15)) * 128 + kk * 32 + (ln >> 4) * 8);
    floatx4 acc[2][4];
    #pragma unroll
    for (int oi = 0; oi < 2; ++oi)
        #pragma unroll
        for (int pi = 0; pi < 4; ++pi) acc[oi][pi] = floatx4{0.f, 0.f, 0.f, 0.f};
    #pragma unroll
    for (int kk = 0; kk < 4; ++kk)
        #pragma unroll
        for (int pi = 0; pi < 4; ++pi) {
            int px = ph + pi * 16 + (ln & 15);
            int cb = kk * 64 + (ln >> 4) * 16;
            short8x bf = *(const short8x*)((const char*)mT + px * 256 + (cb ^ ((px & 7) << 4)));
            #pragma unroll
            for (int oi = 0; oi < 2; ++oi)
                acc[oi][pi] = __builtin_amdgcn_mfma_f32_16x16x32_bf16(aw[oi][kk], bf, acc[oi][pi], 0, 0, 0);
        }
    #pragma unroll
    for (int oi = 0; oi < 2; ++oi) {
        float4 b4 = *(const float4*)(post_b + o0 + oi * 16 + (ln >> 4) * 4);
        float bb[4] = {b4.x, b4.y, b4.z, b4.w};
        #pragma unroll
        for (int pi = 0; pi < 4; ++pi) {
            int pxg = poff + ph + pi * 16 + (ln & 15);
            #pragma unroll
            for (int r = 0; r < 4; ++r) {
                int o = o0 + oi * 16 + (ln >> 4) * 4 + r;
                float val = acc[oi][pi][r] + bb[r] + x[((size_t)b * COUT + o) * HWSZ + pxg];
                skipS[((size_t)b * CD + o) * HWSZ + pxg] = f2bf(val);
            }
        }
    }
}

// ---------------- final BN + ReLU: skipS bf16 -> d_out fp32 ----------------
__global__ __launch_bounds__(256) void bn_relu_out(
        const unsigned short* __restrict__ skipS, float* __restrict__ out,
        const float* __restrict__ stats, const float* __restrict__ g,
        const float* __restrict__ bb) {
    const float N = 262144.f;
    int t = threadIdx.x;
    #pragma unroll
    for (int k = 0; k < 4; ++k) {
        size_t gidx = (size_t)blockIdx.x * 1024 + k * 256 + t;  // 8-elem index
        size_t e = gidx * 8;
        int b = (int)(e >> 20);
        int c = (int)(e >> 14) & 63;
        int px = (int)(e & 16383);
        float mean = stats[c * 2] / N;
        float rstd = rsqrtf(stats[c * 2 + 1] / N - mean * mean + BN_EPS);
        float gc = g[c], bbc = bb[c];
        uint4 v = *(const uint4*)(skipS + ((size_t)b * CD + c) * HWSZ + px);
        unsigned int u[4] = {v.x, v.y, v.z, v.w};
        float4 o0, o1;
        float* op[8] = {&o0.x, &o0.y, &o0.z, &o0.w, &o1.x, &o1.y, &o1.z, &o1.w};
        #pragma unroll
        for (int j = 0; j < 8; ++j) {
            float val = bf2f((unsigned short)((u[j >> 1] >> ((j & 1) * 16)) & 0xffff));
            *op[j] = fmaxf((val - mean) * rstd * gc + bbc, 0.f);
        }
        *(float4*)(out + e) = o0;
        *(float4*)(out + e + 4) = o1;
    }
}

extern "C" void kernel_launch(void* const* d_in, const int* in_sizes, int n_in,
                              void* d_out, int out_size, void* d_ws, size_t ws_size,
                              hipStream_t stream) {
    const float* x          = (const float*)d_in[0];
    const float* pre_w      = (const float*)d_in[1];
    const float* pre_b      = (const float*)d_in[2];
    const float* post_w     = (const float*)d_in[3];
    const float* post_b     = (const float*)d_in[4];
    const float* atten_w    = (const float*)d_in[5];
    const float* atten_b    = (const float*)d_in[6];
    const float* atten_bn_g = (const float*)d_in[7];
    const float* atten_bn_b = (const float*)d_in[8];
    const float* offsets    = (const float*)d_in[9];
    const float* bn_g       = (const float*)d_in[10];
    const float* bn_b       = (const float*)d_in[11];
    float* out = (float*)d_out;
    float* ws  = (float*)d_ws;

    if (ws_size < WS_TOTAL_BYTES) return;

    unsigned short* wAB = (unsigned short*)(ws + WS_WT1);
    unsigned short* wP  = (unsigned short*)(ws + WS_WTP);
    float* disp    = ws + WS_DISP;
    float* a_stats = ws + WS_ASTAT;
    float* o_stats = ws + WS_OSTAT;
    unsigned short* big   = (unsigned short*)(ws + WS_BIG);  // out_pre -> m -> skipS
    unsigned short* a_buf = (unsigned short*)d_out;          // a_raw (bf16)

    hipMemsetAsync((void*)a_stats, 0, 384 * sizeof(float), stream);

    prep_kernel<<<97, 256, 0, stream>>>(pre_w, atten_w, post_w, offsets, ws);
    conv_pre_mfma<<<1024, 256, 0, stream>>>(x, wAB, pre_b, atten_b, big, a_buf);
    chan_stats_bf16<<<dim3(128, 16), 256, 0, stream>>>(a_buf, a_stats);
    displace_bnsp_mul<<<2048, 256, 0, stream>>>(big, a_buf, a_stats, atten_bn_g, atten_bn_b, disp);
    conv_post_mfma<<<2048, 256, 0, stream>>>(big, wP, post_b, x, big);
    chan_stats_bf16<<<dim3(64, 16), 256, 0, stream>>>(big, o_stats);
    bn_relu_out<<<2048, 256, 0, stream>>>(big, out, o_stats, bn_g, bn_b);
}